// Round 1
// baseline (44783.667 us; speedup 1.0000x reference)
//
#include <hip/hip_runtime.h>
#include <hip/hip_bf16.h>

// PathEncoder: B=8, N_NODE=512, N_TOK=8, N_PATHS=256, PATH_LEN=64, VOCAB=50000, H=256
// Round 1: correct f32 implementation, structured for later MFMA conversion.
//
// ws layout (bytes):
//   x       @ 0          4,194,304   [8][512][256] f32  token-maxpooled embeddings
//   base_v  @ 4194304    8,388,608   [8][512][512] f32
//   keys    @ 12582912   8,404,992   [8][513][512] u32  monotonic-encoded scatter-max
//   wTi     @ 20987904   1,572,864   [2][256][768] f32  transposed w_ih (fwd,bwd)
//   wTh     @ 22560768   1,572,864   [2][256][768] f32  transposed w_hh
//   wrT     @ 24133632   1,050,624   [513][512]    f32  transposed w_rank
//   bias4   @ 25184256   8,192       [2][256] float4 {bir+bhr, biz+bhz, bin, bhn}
//   nx      @ 25192448 134,217,728   [2048][64][512] bf16  path GRU outputs
//   total ≈ 159.5 MB

#define HH 256
#define NNODE 512
#define NBATCH 8
#define NPATHS 256
#define PLEN 64
#define G3 768

__device__ __forceinline__ float sigmoidf_(float v) { return 1.f / (1.f + __expf(-v)); }

// monotonic float<->uint encoding for atomicMax-based float max (no NaNs in data)
__device__ __forceinline__ unsigned fkey(float f) {
    unsigned u = __float_as_uint(f);
    return (u & 0x80000000u) ? ~u : (u | 0x80000000u);
}
__device__ __forceinline__ float fdec(unsigned k) {
    unsigned u = (k & 0x80000000u) ? (k ^ 0x80000000u) : ~k;
    return __uint_as_float(u);
}

// ---------------- prep: weight transposes + fused gate biases ----------------
__global__ void k_prep(const float* __restrict__ wf_ih, const float* __restrict__ wb_ih,
                       const float* __restrict__ wf_hh, const float* __restrict__ wb_hh,
                       const float* __restrict__ bf_ih, const float* __restrict__ bf_hh,
                       const float* __restrict__ bb_ih, const float* __restrict__ bb_hh,
                       const float* __restrict__ w_rank,
                       float* __restrict__ wTi, float* __restrict__ wTh,
                       float* __restrict__ wrT, float4* __restrict__ bias4)
{
    int idx = blockIdx.x * 256 + threadIdx.x;
    if (idx < 393216) {                       // [dir][i][g] <- w[g][i]
        const int dir = idx / 196608, r = idx % 196608;
        const int i = r / G3, g = r % G3;
        wTi[idx] = (dir ? wb_ih : wf_ih)[g * HH + i];
        wTh[idx] = (dir ? wb_hh : wf_hh)[g * HH + i];
        return;
    }
    idx -= 393216;
    if (idx < 262656) {                       // wrT[f][o] <- w_rank[o][f]
        const int f = idx / 512, o = idx % 512;
        wrT[idx] = w_rank[o * 513 + f];
        return;
    }
    idx -= 262656;
    if (idx < 512) {
        const int dir = idx >> 8, j = idx & 255;
        const float* bi = dir ? bb_ih : bf_ih;
        const float* bh = dir ? bb_hh : bf_hh;
        bias4[idx] = make_float4(bi[j] + bh[j], bi[256 + j] + bh[256 + j],
                                 bi[512 + j], bh[512 + j]);
    }
}

// ---------------- embedding token max-pool ----------------
__global__ void k_embed(const int* __restrict__ nodes, const float* __restrict__ emb,
                        float* __restrict__ x)
{
    const int bn = blockIdx.x, h = threadIdx.x;
    const int* nd = nodes + bn * 8;
    float m = -3.4e38f;
#pragma unroll
    for (int k = 0; k < 8; ++k)
        m = fmaxf(m, emb[(size_t)nd[k] * HH + h]);
    x[(size_t)bn * HH + h] = m;
}

// ---------------- path GRU scan (both dirs), 16 seqs/block ----------------
// 256 blocks: pb = dir*128 + seqgroup. 256 thr = 4 waves x (16 sq x 4 jq).
// wave wv owns j-quarter [wv*64, wv*64+64): no cross-wave weight redundancy.
__global__ void __launch_bounds__(256, 1)
k_path_scan(const float* __restrict__ x, const int* __restrict__ paths,
            const float* __restrict__ wTi, const float* __restrict__ wTh,
            const float4* __restrict__ bias4, __hip_bfloat16* __restrict__ nx)
{
    __shared__ float smem[2 * 16 * 260];
    const int tid = threadIdx.x;
    const int pb = blockIdx.x;
    const int dir = pb >> 7;
    const int sg = pb & 127;
    const int wv = tid >> 6, lane = tid & 63;
    const int sq = lane >> 2, jq = lane & 3;
    const int jbase = wv * 64 + jq * 16;

    float* xs = smem;            // [16][260]
    float* hsb = smem + 4160;    // [16][260]
    for (int idx = tid; idx < 16 * 260; idx += 256) hsb[idx] = 0.f;

    const int seq0 = sg * 16;
    const float* wi0 = wTi + dir * 196608;
    const float* wh0 = wTh + dir * 196608;

    float a_ir[16], a_iz[16], a_in[16], a_hr[16], a_hz[16], a_hn[16];

    for (int step = 0; step < PLEN; ++step) {
        const int t = dir ? (PLEN - 1 - step) : step;
        // stage 16 gathered x rows (id==512 -> zeros)
        for (int s = 0; s < 16; ++s) {
            const int seq = seq0 + s;
            const int idv = paths[(seq << 6) + t];
            const int b = seq >> 8;
            xs[s * 260 + tid] = (idv < NNODE) ? x[((size_t)(b * NNODE + idv)) * HH + tid] : 0.f;
        }
        __syncthreads();

#pragma unroll
        for (int k = 0; k < 16; ++k) {
            a_ir[k] = 0.f; a_iz[k] = 0.f; a_in[k] = 0.f;
            a_hr[k] = 0.f; a_hz[k] = 0.f; a_hn[k] = 0.f;
        }
        const float* xrow = xs + sq * 260;
        const float* hrow = hsb + sq * 260;
        for (int i = 0; i < HH; i += 4) {
            float4 xv4 = *(const float4*)(xrow + i);
            float4 hv4 = *(const float4*)(hrow + i);
            float xa[4] = {xv4.x, xv4.y, xv4.z, xv4.w};
            float ha[4] = {hv4.x, hv4.y, hv4.z, hv4.w};
#pragma unroll
            for (int u = 0; u < 4; ++u) {
                const float* wi = wi0 + (size_t)(i + u) * G3 + jbase;
                const float* wh = wh0 + (size_t)(i + u) * G3 + jbase;
                const float xv = xa[u], hv = ha[u];
#pragma unroll
                for (int q = 0; q < 4; ++q) {
                    float4 wr = *(const float4*)(wi + q * 4);
                    float4 wz = *(const float4*)(wi + 256 + q * 4);
                    float4 wn = *(const float4*)(wi + 512 + q * 4);
                    a_ir[q * 4 + 0] += xv * wr.x; a_ir[q * 4 + 1] += xv * wr.y;
                    a_ir[q * 4 + 2] += xv * wr.z; a_ir[q * 4 + 3] += xv * wr.w;
                    a_iz[q * 4 + 0] += xv * wz.x; a_iz[q * 4 + 1] += xv * wz.y;
                    a_iz[q * 4 + 2] += xv * wz.z; a_iz[q * 4 + 3] += xv * wz.w;
                    a_in[q * 4 + 0] += xv * wn.x; a_in[q * 4 + 1] += xv * wn.y;
                    a_in[q * 4 + 2] += xv * wn.z; a_in[q * 4 + 3] += xv * wn.w;
                    float4 vr = *(const float4*)(wh + q * 4);
                    float4 vz = *(const float4*)(wh + 256 + q * 4);
                    float4 vn = *(const float4*)(wh + 512 + q * 4);
                    a_hr[q * 4 + 0] += hv * vr.x; a_hr[q * 4 + 1] += hv * vr.y;
                    a_hr[q * 4 + 2] += hv * vr.z; a_hr[q * 4 + 3] += hv * vr.w;
                    a_hz[q * 4 + 0] += hv * vz.x; a_hz[q * 4 + 1] += hv * vz.y;
                    a_hz[q * 4 + 2] += hv * vz.z; a_hz[q * 4 + 3] += hv * vz.w;
                    a_hn[q * 4 + 0] += hv * vn.x; a_hn[q * 4 + 1] += hv * vn.y;
                    a_hn[q * 4 + 2] += hv * vn.z; a_hn[q * 4 + 3] += hv * vn.w;
                }
            }
        }
        // gates
        float hnew[16];
#pragma unroll
        for (int k = 0; k < 16; ++k) {
            const int j = jbase + k;
            const float4 bb = bias4[dir * 256 + j];
            const float r = sigmoidf_(a_ir[k] + a_hr[k] + bb.x);
            const float z = sigmoidf_(a_iz[k] + a_hz[k] + bb.y);
            const float n = tanhf(a_in[k] + bb.z + r * (a_hn[k] + bb.w));
            hnew[k] = (1.f - z) * n + z * hrow[j];
        }
        __syncthreads();
#pragma unroll
        for (int k = 0; k < 16; k += 4)
            *(float4*)(hsb + sq * 260 + jbase + k) =
                make_float4(hnew[k], hnew[k + 1], hnew[k + 2], hnew[k + 3]);
        __hip_bfloat16* nrow = nx + ((size_t)((seq0 + sq) * PLEN + t)) * 512 + dir * 256 + jbase;
#pragma unroll
        for (int k = 0; k < 16; ++k) nrow[k] = __float2bfloat16(hnew[k]);
    }
}

// ---------------- base GRU scan (16 blocks) + rank-proj/scatter-max (8192 blocks) ----
__global__ void k_base_rank(const float* __restrict__ x, const int* __restrict__ paths,
                            const float* __restrict__ wTi, const float* __restrict__ wTh,
                            const float4* __restrict__ bias4,
                            const __hip_bfloat16* __restrict__ nx,
                            const float* __restrict__ wrT, const float* __restrict__ b_rank,
                            float* __restrict__ base_v, unsigned* __restrict__ keys)
{
    __shared__ float smem[16 * 516];
    const int tid = threadIdx.x;
    if (blockIdx.x < 16) {
        // ---- base bidirectional GRU, one block per (dir, b) ----
        const int dir = blockIdx.x >> 3, b = blockIdx.x & 7;
        float* xsr = smem;           // [256]
        float* h = smem + 4160;      // [256]
        h[tid] = 0.f;
        const float* wi0 = wTi + dir * 196608;
        const float* wh0 = wTh + dir * 196608;
        const float4 bb = bias4[dir * 256 + tid];
        for (int step = 0; step < NNODE; ++step) {
            const int t = dir ? (NNODE - 1 - step) : step;
            xsr[tid] = x[((size_t)(b * NNODE + t)) * HH + tid];
            __syncthreads();
            float air = 0.f, aiz = 0.f, ain = 0.f, ahr = 0.f, ahz = 0.f, ahn = 0.f;
            for (int i = 0; i < HH; i += 4) {
                float4 xv4 = *(const float4*)(xsr + i);
                float4 hv4 = *(const float4*)(h + i);
                float xa[4] = {xv4.x, xv4.y, xv4.z, xv4.w};
                float ha[4] = {hv4.x, hv4.y, hv4.z, hv4.w};
#pragma unroll
                for (int u = 0; u < 4; ++u) {
                    const float* wi = wi0 + (size_t)(i + u) * G3 + tid;
                    const float* wh = wh0 + (size_t)(i + u) * G3 + tid;
                    air += xa[u] * wi[0]; aiz += xa[u] * wi[256]; ain += xa[u] * wi[512];
                    ahr += ha[u] * wh[0]; ahz += ha[u] * wh[256]; ahn += ha[u] * wh[512];
                }
            }
            const float r = sigmoidf_(air + ahr + bb.x);
            const float z = sigmoidf_(aiz + ahz + bb.y);
            const float n = tanhf(ain + bb.z + r * (ahn + bb.w));
            const float hnew = (1.f - z) * n + z * h[tid];
            __syncthreads();
            h[tid] = hnew;
            base_v[((size_t)(b * NNODE + t)) * 512 + dir * 256 + tid] = hnew;
        }
    } else {
        // ---- rank projection + scatter-max, 16 entries/block ----
        const int blk = blockIdx.x - 16;
        const int b = blk >> 10;
        const int eg = blk & 1023;
        float* ns = smem;            // [16][516]
        for (int e = 0; e < 16; ++e) {
            const int row = b * 16384 + eg * 16 + e;   // == (b*256+p)*64+l
            const unsigned v = ((const unsigned*)nx)[(size_t)row * 256 + tid];
            ns[e * 516 + 2 * tid] = __uint_as_float(v << 16);
            ns[e * 516 + 2 * tid + 1] = __uint_as_float(v & 0xffff0000u);
        }
        __syncthreads();
        const int wv = tid >> 6, lane = tid & 63;
        const int eq = lane >> 2, oq = lane & 3;
        const int obase = wv * 128 + oq * 32;
        const int ent = eg * 16 + eq;
        const int p = ent >> 6;
        float acc[32];
        const float rv = 1.f / (float)(p + 1);
#pragma unroll
        for (int m = 0; m < 32; ++m)
            acc[m] = b_rank[obase + m] + wrT[512 * 512 + obase + m] * rv;
        const float* nrow = ns + eq * 516;
        for (int f = 0; f < 512; f += 4) {
            float4 nv4 = *(const float4*)(nrow + f);
            float na[4] = {nv4.x, nv4.y, nv4.z, nv4.w};
#pragma unroll
            for (int u = 0; u < 4; ++u) {
                const float* wr = wrT + (size_t)(f + u) * 512 + obase;
                const float nv = na[u];
#pragma unroll
                for (int m4 = 0; m4 < 8; ++m4) {
                    float4 w = *(const float4*)(wr + m4 * 4);
                    acc[m4 * 4 + 0] += nv * w.x; acc[m4 * 4 + 1] += nv * w.y;
                    acc[m4 * 4 + 2] += nv * w.z; acc[m4 * 4 + 3] += nv * w.w;
                }
            }
        }
        const int id = paths[b * 16384 + ent];
        if (id < NNODE) {
            unsigned* kp = keys + ((size_t)(b * (NNODE + 1) + id)) * 512 + obase;
#pragma unroll
            for (int m = 0; m < 32; ++m) {
                const unsigned key = fkey(acc[m]);
                if (key > kp[m]) atomicMax(kp + m, key);
            }
        }
    }
}

// ---------------- merge: v = has ? vmax : transit(x);  all_v = base_v + v ----------------
__global__ void k_merge(const unsigned* __restrict__ keys, const float* __restrict__ base_v,
                        const float* __restrict__ x, const float* __restrict__ w_transit,
                        const float* __restrict__ b_transit, float* __restrict__ out0)
{
    const int blk = blockIdx.x;
    const int b = blk >> 9, n = blk & 511;
    const int tid = threadIdx.x;
#pragma unroll
    for (int h = 0; h < 2; ++h) {
        const int o = tid + h * 256;
        const unsigned k = keys[((size_t)(b * 513 + n)) * 512 + o];
        float v;
        if (k) {
            v = fdec(k);
        } else {
            float a = b_transit[o];
            const float* wt = w_transit + o * HH;
            const float* xr = x + ((size_t)(b * NNODE + n)) * HH;
            for (int i = 0; i < HH; ++i) a += xr[i] * wt[i];
            v = a;
        }
        const size_t oi = ((size_t)(b * NNODE + n)) * 512 + o;
        out0[oi] = base_v[oi] + v;
    }
}

// ---------------- last_state: rowmax over nodes, then @ w_h.T + b_h ----------------
__global__ void k_last(const float* __restrict__ out0, const float* __restrict__ w_h,
                       const float* __restrict__ b_h, float* __restrict__ out1)
{
    __shared__ float m[512];
    const int b = blockIdx.x, tid = threadIdx.x;
#pragma unroll
    for (int h = 0; h < 2; ++h) {
        const int o = tid + h * 256;
        float mm = -3.4e38f;
        for (int n = 0; n < NNODE; ++n)
            mm = fmaxf(mm, out0[((size_t)(b * NNODE + n)) * 512 + o]);
        m[o] = mm;
    }
    __syncthreads();
    float a = b_h[tid];
    const float* wr = w_h + tid * 512;
    for (int j = 0; j < 512; ++j) a += m[j] * wr[j];
    out1[b * HH + tid] = a;
}

extern "C" void kernel_launch(void* const* d_in, const int* in_sizes, int n_in,
                              void* d_out, int out_size, void* d_ws, size_t ws_size,
                              hipStream_t stream)
{
    (void)in_sizes; (void)n_in; (void)out_size; (void)ws_size;
    const int* nodes = (const int*)d_in[0];
    const int* paths = (const int*)d_in[1];
    const float* emb = (const float*)d_in[2];
    const float* wf_ih = (const float*)d_in[3];
    const float* wf_hh = (const float*)d_in[4];
    const float* bf_ih = (const float*)d_in[5];
    const float* bf_hh = (const float*)d_in[6];
    const float* wb_ih = (const float*)d_in[7];
    const float* wb_hh = (const float*)d_in[8];
    const float* bb_ih = (const float*)d_in[9];
    const float* bb_hh = (const float*)d_in[10];
    const float* w_transit = (const float*)d_in[11];
    const float* b_transit = (const float*)d_in[12];
    const float* w_rank = (const float*)d_in[13];
    const float* b_rank = (const float*)d_in[14];
    const float* w_h = (const float*)d_in[15];
    const float* b_h = (const float*)d_in[16];

    char* ws = (char*)d_ws;
    float* x = (float*)(ws);
    float* base_v = (float*)(ws + 4194304);
    unsigned* keys = (unsigned*)(ws + 12582912);
    float* wTi = (float*)(ws + 20987904);
    float* wTh = (float*)(ws + 22560768);
    float* wrT = (float*)(ws + 24133632);
    float4* bias4 = (float4*)(ws + 25184256);
    __hip_bfloat16* nx = (__hip_bfloat16*)(ws + 25192448);

    float* out0 = (float*)d_out;
    float* out1 = out0 + 2097152;

    hipMemsetAsync(keys, 0, 8404992, stream);
    k_prep<<<2564, 256, 0, stream>>>(wf_ih, wb_ih, wf_hh, wb_hh, bf_ih, bf_hh,
                                     bb_ih, bb_hh, w_rank, wTi, wTh, wrT, bias4);
    k_embed<<<4096, 256, 0, stream>>>(nodes, emb, x);
    k_path_scan<<<256, 256, 0, stream>>>(x, paths, wTi, wTh, bias4, nx);
    k_base_rank<<<8208, 256, 0, stream>>>(x, paths, wTi, wTh, bias4, nx, wrT, b_rank,
                                          base_v, keys);
    k_merge<<<4096, 256, 0, stream>>>(keys, base_v, x, w_transit, b_transit, out0);
    k_last<<<8, 256, 0, stream>>>(out0, w_h, b_h, out1);
}

// Round 2
// 3574.408 us; speedup vs baseline: 12.5290x; 12.5290x over previous
//
#include <hip/hip_runtime.h>

// PathEncoder: B=8, N_NODE=512, N_TOK=8, N_PATHS=256, PATH_LEN=64, VOCAB=50000, H=256
// Round 2: MFMA everywhere; recurrent weights register-resident in the scan.
//
// ws layout (bytes):
//   x        @ 0          4,194,304   [4096][256] f32
//   xbf      @ 4194304    2,097,152   [4096][256] bf16
//   xw       @ 6291456   12,586,752   [4097][1536] bf16  x@w_ih.T + b_ih (row 4096 = b_ih pad)
//   whhp     @ 18878208     786,432   packed whh bf16 (per-lane MFMA B-frag order)
//   wih_bt   @ 19664640     786,432   [1536][256] bf16 = concat(wf_ih, wb_ih)
//   wr_bt    @ 20451072     524,288   [512][512]  bf16 = w_rank[:, :512]
//   rank_l   @ 20975360       2,048   [512] f32 = w_rank[:, 512]
//   bias_xw  @ 20977408       6,144   [1536] f32 = concat(bf_ih, bb_ih)
//   keys     @ 20983552   8,404,992   [8][513][512] u32 monotonic scatter-max
//   base_v   @ 29388544   8,388,608   [8][512][512] f32
//   nx       @ 37777152 134,217,728   [131072][512] bf16 path GRU outputs
//   total ≈ 172 MB

#define HH 256
#define NNODE 512
#define PLEN 64

typedef __attribute__((ext_vector_type(8))) short short8;
typedef __attribute__((ext_vector_type(4))) float f32x4;
typedef __attribute__((address_space(1))) const void* gas_t;
typedef __attribute__((address_space(3))) void* las_t;

__device__ __forceinline__ f32x4 mfma16(short8 a, short8 b, f32x4 c) {
    return __builtin_amdgcn_mfma_f32_16x16x32_bf16(a, b, c, 0, 0, 0);
}
__device__ __forceinline__ unsigned short f2bf(float f) {
    unsigned u = __float_as_uint(f);
    u += 0x7fffu + ((u >> 16) & 1u);
    return (unsigned short)(u >> 16);
}
__device__ __forceinline__ float bf2f(unsigned short s) {
    return __uint_as_float(((unsigned)s) << 16);
}
__device__ __forceinline__ float sigm(float x) {
    return __builtin_amdgcn_rcpf(1.f + __expf(-x));
}
__device__ __forceinline__ float tanh_(float x) {
    return 1.f - 2.f * __builtin_amdgcn_rcpf(__expf(2.f * x) + 1.f);
}
__device__ __forceinline__ unsigned fkey(float f) {
    unsigned u = __float_as_uint(f);
    return (u & 0x80000000u) ? ~u : (u | 0x80000000u);
}
__device__ __forceinline__ float fdec(unsigned k) {
    unsigned u = (k & 0x80000000u) ? (k ^ 0x80000000u) : ~k;
    return __uint_as_float(u);
}

// ---------------- embedding token max-pool ----------------
__global__ void k_embed(const int* __restrict__ nodes, const float* __restrict__ emb,
                        float* __restrict__ x, unsigned short* __restrict__ xbf)
{
    const int bn = blockIdx.x, h = threadIdx.x;
    const int* nd = nodes + bn * 8;
    float m = -3.4e38f;
#pragma unroll
    for (int k = 0; k < 8; ++k)
        m = fmaxf(m, emb[(size_t)nd[k] * HH + h]);
    x[(size_t)bn * HH + h] = m;
    xbf[(size_t)bn * HH + h] = f2bf(m);
}

// ---------------- pack weights ----------------
__global__ void k_pack(const float* __restrict__ wf_ih, const float* __restrict__ wf_hh,
                       const float* __restrict__ bf_ih,
                       const float* __restrict__ wb_ih, const float* __restrict__ wb_hh,
                       const float* __restrict__ bb_ih,
                       const float* __restrict__ w_rank,
                       unsigned short* __restrict__ whhp, unsigned short* __restrict__ wih_bt,
                       unsigned short* __restrict__ wr_bt, float* __restrict__ rank_l,
                       float* __restrict__ bias_xw, unsigned short* __restrict__ xw)
{
    int i = blockIdx.x * 256 + threadIdx.x;
    if (i < 393216) {   // whhp: [dir][w][kt][g][lane][e] <- whh[g*256+w*16+(l&15)][kt*32+(l>>4)*8+e]
        const int e = i & 7, l = (i >> 3) & 63, g = (i >> 9) % 3;
        const int kt = (i / 1536) & 7, w = (i / 12288) & 15, dir = i / 196608;
        const float* whh = dir ? wb_hh : wf_hh;
        whhp[i] = f2bf(whh[(g * 256 + w * 16 + (l & 15)) * 256 + kt * 32 + (l >> 4) * 8 + e]);
        return;
    }
    i -= 393216;
    if (i < 393216) {   // wih_bt [1536][256] = concat rows
        const int n = i >> 8, k = i & 255;
        const float* wih = (n < 768) ? wf_ih : wb_ih;
        wih_bt[i] = f2bf(wih[(n % 768) * 256 + k]);
        return;
    }
    i -= 393216;
    if (i < 262144) { wr_bt[i] = f2bf(w_rank[(i >> 9) * 513 + (i & 511)]); return; }
    i -= 262144;
    if (i < 512) { rank_l[i] = w_rank[i * 513 + 512]; return; }
    i -= 512;
    if (i < 1536) {
        const float bv = (i < 768) ? bf_ih[i] : bb_ih[i - 768];
        bias_xw[i] = bv;
        xw[(size_t)4096 * 1536 + i] = f2bf(bv);   // padding row
    }
}

// ---------------- GEMM mainloop (128x128 tile, BK=64, A:[M][K] rm, Bt:[N][K] rm) ----
template<int KD>
__device__ __forceinline__ void gemm_loop(const unsigned short* __restrict__ A,
                                          const unsigned short* __restrict__ Bt,
                                          unsigned short* al, unsigned short* bl,
                                          int bm, int bn, f32x4 acc[4][4])
{
    const int tid = threadIdx.x, w = tid >> 6, l = tid & 63;
    const int lm = l & 15, lh = l >> 4;
    const int wm = w >> 1, wn = w & 1;
    const int lr = l >> 3, lc = (l & 7) * 8;
    for (int k0 = 0; k0 < KD; k0 += 64) {
#pragma unroll
        for (int i = 0; i < 4; ++i) {
            const int c = w * 4 + i;
            const unsigned short* ga = A + (size_t)(bm + c * 8 + lr) * KD + k0 + lc;
            const unsigned short* gb = Bt + (size_t)(bn + c * 8 + lr) * KD + k0 + lc;
            __builtin_amdgcn_global_load_lds((gas_t)ga, (las_t)(al + c * 512), 16, 0, 0);
            __builtin_amdgcn_global_load_lds((gas_t)gb, (las_t)(bl + c * 512), 16, 0, 0);
        }
        __syncthreads();
#pragma unroll
        for (int kt = 0; kt < 2; ++kt) {
            short8 af[4], bfr[4];
            const int ko = kt * 32 + lh * 8;
#pragma unroll
            for (int m = 0; m < 4; ++m)
                af[m] = *(const short8*)(al + (wm * 64 + m * 16 + lm) * 64 + ko);
#pragma unroll
            for (int n = 0; n < 4; ++n)
                bfr[n] = *(const short8*)(bl + (wn * 64 + n * 16 + lm) * 64 + ko);
#pragma unroll
            for (int m = 0; m < 4; ++m)
#pragma unroll
                for (int n = 0; n < 4; ++n)
                    acc[m][n] = mfma16(af[m], bfr[n], acc[m][n]);
        }
        __syncthreads();
    }
}

// ---------------- xw GEMM: [4096][256] @ [256][1536] + bias -> bf16 ----------------
__global__ void __launch_bounds__(256, 2)
k_gemm_xw(const unsigned short* __restrict__ xbf, const unsigned short* __restrict__ wih_bt,
          const float* __restrict__ bias_xw, unsigned short* __restrict__ xw)
{
    __shared__ unsigned short al[128 * 64], bl[128 * 64];
    f32x4 acc[4][4] = {};
    const int bm = blockIdx.y * 128, bn = blockIdx.x * 128;
    gemm_loop<256>(xbf, wih_bt, al, bl, bm, bn, acc);
    const int tid = threadIdx.x, w = tid >> 6, l = tid & 63;
    const int lm = l & 15, lh = l >> 4, wm = w >> 1, wn = w & 1;
#pragma unroll
    for (int m = 0; m < 4; ++m)
#pragma unroll
        for (int rr = 0; rr < 4; ++rr) {
            const int row = bm + wm * 64 + m * 16 + lh * 4 + rr;
#pragma unroll
            for (int n = 0; n < 4; ++n) {
                const int col = bn + wn * 64 + n * 16 + lm;
                xw[(size_t)row * 1536 + col] = f2bf(acc[m][n][rr] + bias_xw[col]);
            }
        }
}

// ---------------- rank GEMM: nx[131072][512] @ wr^T + rank feature + scatter-max ----
__global__ void __launch_bounds__(256, 2)
k_gemm_rank(const unsigned short* __restrict__ nx, const unsigned short* __restrict__ wr_bt,
            const float* __restrict__ b_rank, const float* __restrict__ rank_l,
            const int* __restrict__ paths, unsigned* __restrict__ keys)
{
    __shared__ unsigned short al[128 * 64], bl[128 * 64];
    f32x4 acc[4][4] = {};
    const int bm = blockIdx.y * 128, bn = blockIdx.x * 128;
    gemm_loop<512>(nx, wr_bt, al, bl, bm, bn, acc);
    const int tid = threadIdx.x, w = tid >> 6, l = tid & 63;
    const int lm = l & 15, lh = l >> 4, wm = w >> 1, wn = w & 1;
    const int row0 = bm + wm * 64, col0 = bn + wn * 64;
#pragma unroll
    for (int m = 0; m < 4; ++m)
#pragma unroll
        for (int rr = 0; rr < 4; ++rr) {
            const int grow = row0 + m * 16 + lh * 4 + rr;
            const int id = paths[grow];
            const int b = grow >> 14;
            const float rv = __builtin_amdgcn_rcpf((float)(((grow >> 6) & 255) + 1));
            unsigned* kp = keys + (((size_t)(b * 513 + (id < 512 ? id : 512))) << 9);
#pragma unroll
            for (int n = 0; n < 4; ++n) {
                const int col = col0 + n * 16 + lm;
                const float v = acc[m][n][rr] + b_rank[col] + rank_l[col] * rv;
                if (id < 512) {
                    const unsigned key = fkey(v);
                    if (key > kp[col]) atomicMax(kp + col, key);
                }
            }
        }
}

// ---------------- fused GRU scan: blocks 0-1 = base (M=8, 512 steps), 2-257 = path ----
// 1024 thr = 16 waves; wave w owns hidden units [w*16, w*16+16) x 3 gates.
// whh held in registers (24 x short8 / lane); h in swizzled LDS; 1 barrier/step.
__global__ void __launch_bounds__(1024, 1)
k_scan(const int* __restrict__ paths, const unsigned short* __restrict__ xw,
       const unsigned short* __restrict__ whhp,
       const float* __restrict__ bf_hh, const float* __restrict__ bb_hh,
       unsigned short* __restrict__ nx, float* __restrict__ base_v)
{
    __shared__ unsigned short hl[2][16 * 256];
    __shared__ int idr[16 * 64];

    const int tid = threadIdx.x;
    const int w = tid >> 6, l = tid & 63;
    const int lm = l & 15, lh = l >> 4;
    const bool isBase = blockIdx.x < 2;
    const int dir = isBase ? blockIdx.x : ((blockIdx.x - 2) >> 7);
    const int sg = isBase ? 0 : ((blockIdx.x - 2) & 127);
    const int nsteps = isBase ? NNODE : PLEN;
    const int jcol = w * 16 + lm;

    // register-resident B fragments (whh packed)
    short8 Bf[8][3];
    {
        const unsigned short* wp = whhp + ((size_t)(dir * 16 + w) * 24) * 512 + l * 8;
#pragma unroll
        for (int kt = 0; kt < 8; ++kt)
#pragma unroll
            for (int g = 0; g < 3; ++g)
                Bf[kt][g] = *(const short8*)(wp + (kt * 3 + g) * 512);
    }
    const float* bhh = dir ? bb_hh : bf_hh;
    const float bhr = bhh[jcol], bhz = bhh[256 + jcol], bhn = bhh[512 + jcol];

    if (!isBase) {
        const int s = tid >> 6, t = tid & 63;     // 1024 threads = exactly 16x64
        const int seq = sg * 16 + s;
        const int id = paths[(seq << 6) + t];
        idr[tid] = (id < NNODE) ? ((seq >> 8) * NNODE + id) : 4096;
    }
    for (int i = tid; i < 4096; i += 1024) hl[0][i] = 0;
    float ho[4] = {0.f, 0.f, 0.f, 0.f};
    __syncthreads();

    int cur = 0;
    for (int step = 0; step < nsteps; ++step) {
        const int t = dir ? (nsteps - 1 - step) : step;

        // gather xw for this step's inputs (hidden under the MFMA chain)
        float xwr[4], xwz[4], xwn[4];
#pragma unroll
        for (int ri = 0; ri < 4; ++ri) {
            const int r = lh * 4 + ri;
            const int row = isBase ? ((r < 8) ? (r * NNODE + t) : 4096) : idr[r * 64 + t];
            const unsigned short* xp = xw + (size_t)row * 1536 + dir * 768 + jcol;
            xwr[ri] = bf2f(xp[0]);
            xwz[ri] = bf2f(xp[256]);
            xwn[ri] = bf2f(xp[512]);
        }

        // gates = h @ whh^T  (M=16 seqs, N=48 own cols, K=256)
        f32x4 acc0 = {}, acc1 = {}, acc2 = {};
        const unsigned short* hcur = hl[cur];
#pragma unroll
        for (int kt = 0; kt < 8; ++kt) {
            const int boff = (lm * 512 + kt * 64 + lh * 16) ^ ((lm & 7) << 4);
            const short8 a = *(const short8*)((const char*)hcur + boff);
            acc0 = mfma16(a, Bf[kt][0], acc0);
            acc1 = mfma16(a, Bf[kt][1], acc1);
            acc2 = mfma16(a, Bf[kt][2], acc2);
        }

        unsigned short* hnxt = hl[cur ^ 1];
#pragma unroll
        for (int ri = 0; ri < 4; ++ri) {
            const int seq = lh * 4 + ri;
            const float rr = sigm(acc0[ri] + bhr + xwr[ri]);
            const float zz = sigm(acc1[ri] + bhz + xwz[ri]);
            const float nn = tanh_(xwn[ri] + rr * (acc2[ri] + bhn));
            const float hn = (1.f - zz) * nn + zz * ho[ri];
            ho[ri] = hn;
            const int wb = (seq * 512 + jcol * 2) ^ ((seq & 7) << 4);
            *(unsigned short*)((char*)hnxt + wb) = f2bf(hn);
            if (isBase) {
                if (seq < 8)
                    base_v[((size_t)(seq * NNODE + t)) * 512 + dir * 256 + jcol] = hn;
            } else {
                nx[((size_t)((sg * 16 + seq) * PLEN + t)) * 512 + dir * 256 + jcol] = f2bf(hn);
            }
        }
        __syncthreads();
        cur ^= 1;
    }
}

// ---------------- merge: v = has ? vmax : transit(x);  all_v = base_v + v ----------------
__global__ void k_merge(const unsigned* __restrict__ keys, const float* __restrict__ base_v,
                        const float* __restrict__ x, const float* __restrict__ w_transit,
                        const float* __restrict__ b_transit, float* __restrict__ out0)
{
    const int blk = blockIdx.x;
    const int b = blk >> 9, n = blk & 511;
    const int tid = threadIdx.x;
#pragma unroll
    for (int h = 0; h < 2; ++h) {
        const int o = tid + h * 256;
        const unsigned k = keys[((size_t)(b * 513 + n)) * 512 + o];
        float v;
        if (k) {
            v = fdec(k);
        } else {
            float a = b_transit[o];
            const float* wt = w_transit + o * HH;
            const float* xr = x + ((size_t)(b * NNODE + n)) * HH;
            for (int i = 0; i < HH; ++i) a += xr[i] * wt[i];
            v = a;
        }
        const size_t oi = ((size_t)(b * NNODE + n)) * 512 + o;
        out0[oi] = base_v[oi] + v;
    }
}

// ---------------- last_state: rowmax over nodes, then @ w_h.T + b_h ----------------
__global__ void k_last(const float* __restrict__ out0, const float* __restrict__ w_h,
                       const float* __restrict__ b_h, float* __restrict__ out1)
{
    __shared__ float m[512];
    const int b = blockIdx.x, tid = threadIdx.x;
#pragma unroll
    for (int h = 0; h < 2; ++h) {
        const int o = tid + h * 256;
        float mm = -3.4e38f;
        for (int n = 0; n < NNODE; ++n)
            mm = fmaxf(mm, out0[((size_t)(b * NNODE + n)) * 512 + o]);
        m[o] = mm;
    }
    __syncthreads();
    float a = b_h[tid];
    const float* wr = w_h + tid * 512;
    for (int j = 0; j < 512; ++j) a += m[j] * wr[j];
    out1[b * HH + tid] = a;
}

extern "C" void kernel_launch(void* const* d_in, const int* in_sizes, int n_in,
                              void* d_out, int out_size, void* d_ws, size_t ws_size,
                              hipStream_t stream)
{
    (void)in_sizes; (void)n_in; (void)out_size; (void)ws_size;
    const int* nodes = (const int*)d_in[0];
    const int* paths = (const int*)d_in[1];
    const float* emb = (const float*)d_in[2];
    const float* wf_ih = (const float*)d_in[3];
    const float* wf_hh = (const float*)d_in[4];
    const float* bf_ih = (const float*)d_in[5];
    const float* bf_hh = (const float*)d_in[6];
    const float* wb_ih = (const float*)d_in[7];
    const float* wb_hh = (const float*)d_in[8];
    const float* bb_ih = (const float*)d_in[9];
    const float* bb_hh = (const float*)d_in[10];
    const float* w_transit = (const float*)d_in[11];
    const float* b_transit = (const float*)d_in[12];
    const float* w_rank = (const float*)d_in[13];
    const float* b_rank = (const float*)d_in[14];
    const float* w_h = (const float*)d_in[15];
    const float* b_h = (const float*)d_in[16];

    char* ws = (char*)d_ws;
    float* x = (float*)(ws);
    unsigned short* xbf = (unsigned short*)(ws + 4194304);
    unsigned short* xw = (unsigned short*)(ws + 6291456);
    unsigned short* whhp = (unsigned short*)(ws + 18878208);
    unsigned short* wih_bt = (unsigned short*)(ws + 19664640);
    unsigned short* wr_bt = (unsigned short*)(ws + 20451072);
    float* rank_l = (float*)(ws + 20975360);
    float* bias_xw = (float*)(ws + 20977408);
    unsigned* keys = (unsigned*)(ws + 20983552);
    float* base_v = (float*)(ws + 29388544);
    unsigned short* nx = (unsigned short*)(ws + 37777152);

    float* out0 = (float*)d_out;
    float* out1 = out0 + 2097152;

    hipMemsetAsync(keys, 0, 8404992, stream);
    k_embed<<<4096, 256, 0, stream>>>(nodes, emb, x, xbf);
    k_pack<<<4104, 256, 0, stream>>>(wf_ih, wf_hh, bf_ih, wb_ih, wb_hh, bb_ih,
                                     w_rank, whhp, wih_bt, wr_bt, rank_l, bias_xw, xw);
    k_gemm_xw<<<dim3(12, 32), 256, 0, stream>>>(xbf, wih_bt, bias_xw, xw);
    k_scan<<<258, 1024, 0, stream>>>(paths, xw, whhp, bf_hh, bb_hh, nx, base_v);
    k_gemm_rank<<<dim3(4, 1024), 256, 0, stream>>>(nx, wr_bt, b_rank, rank_l, paths, keys);
    k_merge<<<4096, 256, 0, stream>>>(keys, base_v, x, w_transit, b_transit, out0);
    k_last<<<8, 256, 0, stream>>>(out0, w_h, b_h, out1);
}

// Round 3
// 2517.366 us; speedup vs baseline: 17.7899x; 1.4199x over previous
//
#include <hip/hip_runtime.h>

// PathEncoder: B=8, N_NODE=512, N_TOK=8, N_PATHS=256, PATH_LEN=64, VOCAB=50000, H=256
// Round 3: register-resident recurrent weights (512thr/8-wave, cap 256 VGPR),
// rank GEMM fused into path blocks (overlaps base GRU tail), 12B packed gathers.
//
// ws layout (bytes):
//   x       @ 0          4,194,304   [4096][256] f32
//   xbf     @ 4194304    2,097,152   [4096][256] bf16
//   xw3     @ 6291456   12,585,984   [4097] rows x 1536 bf16, lane-packed layout:
//                                    row*1536 + dir*768 + w*96 + lm*6 + g*2 + n
//   whhp    @ 18877440     786,432   packed whh bf16 MFMA B-frags
//   wih_bt  @ 19663872     786,432   [1536][256] bf16 concat(wf_ih, wb_ih)
//   wr_bt   @ 20450304     524,288   [512][512] bf16 w_rank[:, :512]
//   rank_l  @ 20974592       2,048   [512] f32 w_rank[:, 512]
//   bias2   @ 20976640       6,144   [1536] f32 b_ih + (bhh for r,z gates)
//   keys    @ 20982784   8,404,992   [8][513][512] u32 scatter-max
//   base_v  @ 29387776   8,388,608   [8][512][512] f32
//   nx      @ 37776384 134,217,728   [131072][512] bf16
//   total ≈ 172 MB

#define HH 256
#define NNODE 512
#define PLEN 64

typedef __attribute__((ext_vector_type(8))) short short8;
typedef __attribute__((ext_vector_type(4))) float f32x4;
typedef unsigned short ushort_t;
typedef __attribute__((address_space(1))) const void* gas_t;
typedef __attribute__((address_space(3))) void* las_t;

__device__ __forceinline__ f32x4 mfma16(short8 a, short8 b, f32x4 c) {
    return __builtin_amdgcn_mfma_f32_16x16x32_bf16(a, b, c, 0, 0, 0);
}
__device__ __forceinline__ ushort_t f2bf(float f) {
    unsigned u = __float_as_uint(f);
    u += 0x7fffu + ((u >> 16) & 1u);
    return (ushort_t)(u >> 16);
}
__device__ __forceinline__ float bf2f(ushort_t s) {
    return __uint_as_float(((unsigned)s) << 16);
}
__device__ __forceinline__ float sigm(float x) {
    return __builtin_amdgcn_rcpf(1.f + __expf(-x));
}
__device__ __forceinline__ float tanh_(float x) {
    return 1.f - 2.f * __builtin_amdgcn_rcpf(__expf(2.f * x) + 1.f);
}
__device__ __forceinline__ unsigned fkey(float f) {
    unsigned u = __float_as_uint(f);
    return (u & 0x80000000u) ? ~u : (u | 0x80000000u);
}
__device__ __forceinline__ float fdec(unsigned k) {
    unsigned u = (k & 0x80000000u) ? (k ^ 0x80000000u) : ~k;
    return __uint_as_float(u);
}

// xw3 remap: col c in [0,1536) -> packed element offset within a row
__device__ __forceinline__ int xw3_remap(int c) {
    const int dir = c >= 768;
    const int cd = c - dir * 768;
    const int g = cd >> 8, cc = cd & 255;
    const int w2 = cc >> 5, nn = (cc >> 4) & 1, lmm = cc & 15;
    return dir * 768 + w2 * 96 + lmm * 6 + g * 2 + nn;
}

// ---------------- embedding token max-pool ----------------
__global__ void k_embed(const int* __restrict__ nodes, const float* __restrict__ emb,
                        float* __restrict__ x, ushort_t* __restrict__ xbf)
{
    const int bn = blockIdx.x, h = threadIdx.x;
    const int* nd = nodes + bn * 8;
    float m = -3.4e38f;
#pragma unroll
    for (int k = 0; k < 8; ++k)
        m = fmaxf(m, emb[(size_t)nd[k] * HH + h]);
    x[(size_t)bn * HH + h] = m;
    xbf[(size_t)bn * HH + h] = f2bf(m);
}

// ---------------- pack weights ----------------
__global__ void k_pack(const float* __restrict__ wf_ih, const float* __restrict__ wf_hh,
                       const float* __restrict__ bf_ih, const float* __restrict__ bf_hh,
                       const float* __restrict__ wb_ih, const float* __restrict__ wb_hh,
                       const float* __restrict__ bb_ih, const float* __restrict__ bb_hh,
                       const float* __restrict__ w_rank,
                       ushort_t* __restrict__ whhp, ushort_t* __restrict__ wih_bt,
                       ushort_t* __restrict__ wr_bt, float* __restrict__ rank_l,
                       float* __restrict__ bias2, ushort_t* __restrict__ xw3)
{
    int i = blockIdx.x * 256 + threadIdx.x;
    if (i < 393216) {
        // whhp[(((dir*8+w)*8+kt)*3+g)*2+n][l][e] <- whh[g*256+w*32+n*16+(l&15)][kt*32+(l>>4)*8+e]
        const int e = i & 7, l = (i >> 3) & 63;
        int r = i >> 9;
        const int n = r & 1; r >>= 1;
        const int g = r % 3; r /= 3;
        const int kt = r & 7; r >>= 3;
        const int w2 = r & 7;
        const int dir = r >> 3;
        const float* whh = dir ? wb_hh : wf_hh;
        whhp[i] = f2bf(whh[(g * 256 + w2 * 32 + n * 16 + (l & 15)) * 256 +
                           kt * 32 + (l >> 4) * 8 + e]);
        return;
    }
    i -= 393216;
    if (i < 393216) {   // wih_bt [1536][256]
        const int n = i >> 8, k = i & 255;
        const float* wih = (n < 768) ? wf_ih : wb_ih;
        wih_bt[i] = f2bf(wih[(n % 768) * 256 + k]);
        return;
    }
    i -= 393216;
    if (i < 262144) { wr_bt[i] = f2bf(w_rank[(i >> 9) * 513 + (i & 511)]); return; }
    i -= 262144;
    if (i < 512) { rank_l[i] = w_rank[i * 513 + 512]; return; }
    i -= 512;
    if (i < 1536) {
        const int c = i;
        const int dir = c >= 768;
        const int cd = c - dir * 768;
        const int g = cd >> 8;
        const float bi = dir ? bb_ih[cd] : bf_ih[cd];
        const float bh = (g < 2) ? (dir ? bb_hh[cd] : bf_hh[cd]) : 0.f;
        bias2[c] = bi + bh;
        xw3[(size_t)4096 * 1536 + xw3_remap(c)] = f2bf(bi + bh);  // padding row
    }
}

// ---------------- GEMM mainloop (256 thr, 128x128, BK=64; A,Bt row-major [*][K]) ----
template<int KD>
__device__ __forceinline__ void gemm_loop(const ushort_t* __restrict__ A,
                                          const ushort_t* __restrict__ Bt,
                                          ushort_t* al, ushort_t* bl,
                                          int bm, int bn, f32x4 acc[4][4])
{
    const int tid = threadIdx.x, w = tid >> 6, l = tid & 63;
    const int lm = l & 15, lh = l >> 4;
    const int wm = w >> 1, wn = w & 1;
    const int lr = l >> 3, lc = (l & 7) * 8;
    for (int k0 = 0; k0 < KD; k0 += 64) {
#pragma unroll
        for (int i = 0; i < 4; ++i) {
            const int c = w * 4 + i;
            const ushort_t* ga = A + (size_t)(bm + c * 8 + lr) * KD + k0 + lc;
            const ushort_t* gb = Bt + (size_t)(bn + c * 8 + lr) * KD + k0 + lc;
            __builtin_amdgcn_global_load_lds((gas_t)ga, (las_t)(al + c * 512), 16, 0, 0);
            __builtin_amdgcn_global_load_lds((gas_t)gb, (las_t)(bl + c * 512), 16, 0, 0);
        }
        __syncthreads();
#pragma unroll
        for (int kt = 0; kt < 2; ++kt) {
            short8 af[4], bfr[4];
            const int ko = kt * 32 + lh * 8;
#pragma unroll
            for (int m = 0; m < 4; ++m)
                af[m] = *(const short8*)(al + (wm * 64 + m * 16 + lm) * 64 + ko);
#pragma unroll
            for (int n = 0; n < 4; ++n)
                bfr[n] = *(const short8*)(bl + (wn * 64 + n * 16 + lm) * 64 + ko);
#pragma unroll
            for (int m = 0; m < 4; ++m)
#pragma unroll
                for (int n = 0; n < 4; ++n)
                    acc[m][n] = mfma16(af[m], bfr[n], acc[m][n]);
        }
        __syncthreads();
    }
}

// ---------------- xw GEMM: [4096][256] @ [256][1536] + bias2 -> packed bf16 ----------
__global__ void __launch_bounds__(256, 2)
k_gemm_xw(const ushort_t* __restrict__ xbf, const ushort_t* __restrict__ wih_bt,
          const float* __restrict__ bias2, ushort_t* __restrict__ xw3)
{
    __shared__ __align__(16) ushort_t al[128 * 64], bl[128 * 64];
    f32x4 acc[4][4] = {};
    const int bm = blockIdx.y * 128, bn = blockIdx.x * 128;
    gemm_loop<256>(xbf, wih_bt, al, bl, bm, bn, acc);
    const int tid = threadIdx.x, w = tid >> 6, l = tid & 63;
    const int lm = l & 15, lh = l >> 4, wm = w >> 1, wn = w & 1;
#pragma unroll
    for (int m = 0; m < 4; ++m)
#pragma unroll
        for (int rr = 0; rr < 4; ++rr) {
            const int row = bm + wm * 64 + m * 16 + lh * 4 + rr;
#pragma unroll
            for (int n = 0; n < 4; ++n) {
                const int col = bn + wn * 64 + n * 16 + lm;
                xw3[(size_t)row * 1536 + xw3_remap(col)] = f2bf(acc[m][n][rr] + bias2[col]);
            }
        }
}

// ---------------- fused scan + rank ----------------
// 130 blocks x 512 thr. Blocks 0,1: base GRU (dir=blockIdx, M=8, 512 steps).
// Blocks 2..129: 16 path seqs, scan fwd then bwd (64 steps each), then rank
// GEMM + scatter-max over own 1024 nx rows (32 jobs of 128x128, K=512).
__global__ void __launch_bounds__(512, 2)
k_scan(const int* __restrict__ paths, const ushort_t* __restrict__ xw3,
       const ushort_t* __restrict__ whhp,
       const float* __restrict__ bf_hh, const float* __restrict__ bb_hh,
       const ushort_t* __restrict__ wr_bt, const float* __restrict__ b_rank,
       const float* __restrict__ rank_l,
       ushort_t* __restrict__ nx, float* __restrict__ base_v,
       unsigned* __restrict__ keys)
{
    __shared__ __align__(16) ushort_t hl[2][4096];
    __shared__ __align__(16) ushort_t al[8192], bl[8192];
    __shared__ int idr[1024];

    const int tid = threadIdx.x;
    const int w = tid >> 6, l = tid & 63;
    const int lm = l & 15, lh = l >> 4;
    const bool isBase = blockIdx.x < 2;
    const int sg = (int)blockIdx.x - 2;

    if (!isBase) {
        for (int i = tid; i < 1024; i += 512) {
            const int s = sg * 16 + (i >> 6), t = i & 63;
            const int id = paths[(s << 6) + t];
            idr[i] = (id < NNODE) ? (((s >> 8) << 9) + id) : 4096;
        }
    }

    const int ndir = isBase ? 1 : 2;
    const int nsteps = isBase ? NNODE : PLEN;

    for (int di = 0; di < ndir; ++di) {
        const int dir = isBase ? (int)blockIdx.x : di;
        // register-resident recurrent weights: 48 x short8 = 192 VGPR
        short8 Bf[8][3][2];
        {
            const ushort_t* wp = whhp + (size_t)(dir * 8 + w) * 24576 + l * 8;
#pragma unroll
            for (int kt = 0; kt < 8; ++kt)
#pragma unroll
                for (int g = 0; g < 3; ++g)
#pragma unroll
                    for (int n = 0; n < 2; ++n)
                        Bf[kt][g][n] = *(const short8*)(wp + (kt * 6 + g * 2 + n) * 512);
        }
        const float* bhh = dir ? bb_hh : bf_hh;
        const float bhn0 = bhh[512 + w * 32 + lm];
        const float bhn1 = bhh[512 + w * 32 + 16 + lm];

        __syncthreads();
        for (int i = tid; i < 4096; i += 512) hl[0][i] = 0;
        float ho[4][2] = {};
        __syncthreads();

        int cur = 0;
        for (int step = 0; step < nsteps; ++step) {
            const int t = dir ? (nsteps - 1 - step) : step;
            // packed 12B gather per (lane, ri): 6 bf16 = {r,z,n} x {n0,n1}
            unsigned gr[4], gz[4], gn[4];
#pragma unroll
            for (int ri = 0; ri < 4; ++ri) {
                const int sq = lh * 4 + ri;
                const int row = isBase ? ((sq < 8) ? ((sq << 9) + t) : 4096)
                                       : idr[(sq << 6) + t];
                const unsigned* gp = (const unsigned*)((const char*)xw3 +
                    (size_t)row * 3072 + dir * 1536 + w * 192 + lm * 12);
                gr[ri] = gp[0]; gz[ri] = gp[1]; gn[ri] = gp[2];
            }
            // gates = h @ whh^T: M=16 seqs, own 96 cols, K=256
            f32x4 acc[3][2] = {};
            {
                const char* hb = (const char*)hl[cur];
#pragma unroll
                for (int kt = 0; kt < 8; ++kt) {
                    const short8 a = *(const short8*)(hb + lm * 512 +
                        ((kt * 64 + lh * 16) ^ ((lm & 7) << 4)));
#pragma unroll
                    for (int g = 0; g < 3; ++g)
#pragma unroll
                        for (int n = 0; n < 2; ++n)
                            acc[g][n] = mfma16(a, Bf[kt][g][n], acc[g][n]);
                }
            }
            ushort_t* hn_ = hl[cur ^ 1];
#pragma unroll
            for (int ri = 0; ri < 4; ++ri) {
                const int sq = lh * 4 + ri;
#pragma unroll
                for (int n = 0; n < 2; ++n) {
                    const float xr = bf2f((ushort_t)(n ? (gr[ri] >> 16) : (gr[ri] & 0xffffu)));
                    const float xz = bf2f((ushort_t)(n ? (gz[ri] >> 16) : (gz[ri] & 0xffffu)));
                    const float xn = bf2f((ushort_t)(n ? (gn[ri] >> 16) : (gn[ri] & 0xffffu)));
                    const float rr = sigm(acc[0][n][ri] + xr);
                    const float zz = sigm(acc[1][n][ri] + xz);
                    const float nn = tanh_(xn + rr * (acc[2][n][ri] + (n ? bhn1 : bhn0)));
                    const float h = (1.f - zz) * nn + zz * ho[ri][n];
                    ho[ri][n] = h;
                    const int col = w * 32 + n * 16 + lm;
                    const ushort_t hb16 = f2bf(h);
                    *(ushort_t*)((char*)hn_ + sq * 512 + ((col * 2) ^ ((sq & 7) << 4))) = hb16;
                    if (isBase) {
                        if (sq < 8)
                            base_v[((size_t)(sq * NNODE + t)) * 512 + dir * 256 + col] = h;
                    } else {
                        nx[((size_t)((sg * 16 + sq) * PLEN + t)) * 512 + dir * 256 + col] = hb16;
                    }
                }
            }
            __syncthreads();
            cur ^= 1;
        }
    }
    if (isBase) return;

    // ---- rank phase: own 1024 nx rows @ wr^T, 8 waves on 128x128 tiles ----
    __threadfence_block();
    __syncthreads();
    const int wm = w >> 2, wn = w & 3;   // wave tile 64x32
#pragma unroll 1
    for (int job = 0; job < 32; ++job) {
        const int mt = job >> 2, ntile = job & 3;
        const size_t ar0 = (size_t)sg * 1024 + mt * 128;
        const int n0 = ntile * 128;
        f32x4 racc[4][2] = {};
        for (int k0 = 0; k0 < 512; k0 += 64) {
#pragma unroll
            for (int i = 0; i < 2; ++i) {
                const int c = w * 128 + i * 64 + l;
                const int row = c >> 3, j = c & 7;
                const int jp = j ^ (row & 7);   // pre-swizzled source (both-sides rule)
                __builtin_amdgcn_global_load_lds(
                    (gas_t)(nx + (ar0 + row) * 512 + k0 + jp * 8),
                    (las_t)(al + c * 8), 16, 0, 0);
                __builtin_amdgcn_global_load_lds(
                    (gas_t)(wr_bt + (size_t)(n0 + row) * 512 + k0 + jp * 8),
                    (las_t)(bl + c * 8), 16, 0, 0);
            }
            __syncthreads();
#pragma unroll
            for (int kt = 0; kt < 2; ++kt) {
                short8 av[4], bv[2];
#pragma unroll
                for (int m = 0; m < 4; ++m) {
                    const int r = wm * 64 + m * 16 + lm;
                    av[m] = *(const short8*)((const char*)al + r * 128 +
                            ((kt * 64 + lh * 16) ^ ((r & 7) << 4)));
                }
#pragma unroll
                for (int n = 0; n < 2; ++n) {
                    const int r = wn * 32 + n * 16 + lm;
                    bv[n] = *(const short8*)((const char*)bl + r * 128 +
                            ((kt * 64 + lh * 16) ^ ((r & 7) << 4)));
                }
#pragma unroll
                for (int m = 0; m < 4; ++m)
#pragma unroll
                    for (int n = 0; n < 2; ++n)
                        racc[m][n] = mfma16(av[m], bv[n], racc[m][n]);
            }
            __syncthreads();
        }
#pragma unroll
        for (int m = 0; m < 4; ++m)
#pragma unroll
            for (int rr = 0; rr < 4; ++rr) {
                const size_t grow = ar0 + wm * 64 + m * 16 + lh * 4 + rr;
                const int id = paths[grow];
                const float rv = __builtin_amdgcn_rcpf((float)(((grow >> 6) & 255) + 1));
                unsigned* kp = keys + (((grow >> 14) * 513 + id) << 9);
#pragma unroll
                for (int n = 0; n < 2; ++n) {
                    const int col = n0 + wn * 32 + n * 16 + lm;
                    const float v = racc[m][n][rr] + b_rank[col] + rank_l[col] * rv;
                    if (id < NNODE) {
                        const unsigned key = fkey(v);
                        if (key > kp[col]) atomicMax(kp + col, key);
                    }
                }
            }
    }
}

// ---------------- merge: v = has ? vmax : transit(x);  all_v = base_v + v ----------------
__global__ void k_merge(const unsigned* __restrict__ keys, const float* __restrict__ base_v,
                        const float* __restrict__ x, const float* __restrict__ w_transit,
                        const float* __restrict__ b_transit, float* __restrict__ out0)
{
    const int blk = blockIdx.x;
    const int b = blk >> 9, n = blk & 511;
    const int tid = threadIdx.x;
#pragma unroll
    for (int h = 0; h < 2; ++h) {
        const int o = tid + h * 256;
        const unsigned k = keys[((size_t)(b * 513 + n)) * 512 + o];
        float v;
        if (k) {
            v = fdec(k);
        } else {
            float a = b_transit[o];
            const float* wt = w_transit + o * HH;
            const float* xr = x + ((size_t)(b * NNODE + n)) * HH;
            for (int i = 0; i < HH; ++i) a += xr[i] * wt[i];
            v = a;
        }
        const size_t oi = ((size_t)(b * NNODE + n)) * 512 + o;
        out0[oi] = base_v[oi] + v;
    }
}

// ---------------- last_state: rowmax over nodes, then @ w_h.T + b_h ----------------
__global__ void k_last(const float* __restrict__ out0, const float* __restrict__ w_h,
                       const float* __restrict__ b_h, float* __restrict__ out1)
{
    __shared__ float m[512];
    const int b = blockIdx.x, tid = threadIdx.x;
#pragma unroll
    for (int h = 0; h < 2; ++h) {
        const int o = tid + h * 256;
        float mm = -3.4e38f;
        for (int n = 0; n < NNODE; ++n)
            mm = fmaxf(mm, out0[((size_t)(b * NNODE + n)) * 512 + o]);
        m[o] = mm;
    }
    __syncthreads();
    float a = b_h[tid];
    const float* wr = w_h + tid * 512;
    for (int j = 0; j < 512; ++j) a += m[j] * wr[j];
    out1[b * HH + tid] = a;
}

extern "C" void kernel_launch(void* const* d_in, const int* in_sizes, int n_in,
                              void* d_out, int out_size, void* d_ws, size_t ws_size,
                              hipStream_t stream)
{
    (void)in_sizes; (void)n_in; (void)out_size; (void)ws_size;
    const int* nodes = (const int*)d_in[0];
    const int* paths = (const int*)d_in[1];
    const float* emb = (const float*)d_in[2];
    const float* wf_ih = (const float*)d_in[3];
    const float* wf_hh = (const float*)d_in[4];
    const float* bf_ih = (const float*)d_in[5];
    const float* bf_hh = (const float*)d_in[6];
    const float* wb_ih = (const float*)d_in[7];
    const float* wb_hh = (const float*)d_in[8];
    const float* bb_ih = (const float*)d_in[9];
    const float* bb_hh = (const float*)d_in[10];
    const float* w_transit = (const float*)d_in[11];
    const float* b_transit = (const float*)d_in[12];
    const float* w_rank = (const float*)d_in[13];
    const float* b_rank = (const float*)d_in[14];
    const float* w_h = (const float*)d_in[15];
    const float* b_h = (const float*)d_in[16];

    char* ws = (char*)d_ws;
    float* x = (float*)(ws);
    ushort_t* xbf = (ushort_t*)(ws + 4194304);
    ushort_t* xw3 = (ushort_t*)(ws + 6291456);
    ushort_t* whhp = (ushort_t*)(ws + 18877440);
    ushort_t* wih_bt = (ushort_t*)(ws + 19663872);
    ushort_t* wr_bt = (ushort_t*)(ws + 20450304);
    float* rank_l = (float*)(ws + 20974592);
    float* bias2 = (float*)(ws + 20976640);
    unsigned* keys = (unsigned*)(ws + 20982784);
    float* base_v = (float*)(ws + 29387776);
    ushort_t* nx = (ushort_t*)(ws + 37776384);

    float* out0 = (float*)d_out;
    float* out1 = out0 + 2097152;

    hipMemsetAsync(keys, 0, 8404992, stream);
    k_embed<<<4096, 256, 0, stream>>>(nodes, emb, x, xbf);
    k_pack<<<4104, 256, 0, stream>>>(wf_ih, wf_hh, bf_ih, bf_hh, wb_ih, wb_hh,
                                     bb_ih, bb_hh, w_rank,
                                     whhp, wih_bt, wr_bt, rank_l, bias2, xw3);
    k_gemm_xw<<<dim3(12, 32), 256, 0, stream>>>(xbf, wih_bt, bias2, xw3);
    k_scan<<<130, 512, 0, stream>>>(paths, xw3, whhp, bf_hh, bb_hh, wr_bt,
                                    b_rank, rank_l, nx, base_v, keys);
    k_merge<<<4096, 256, 0, stream>>>(keys, base_v, x, w_transit, b_transit, out0);
    k_last<<<8, 256, 0, stream>>>(out0, w_h, b_h, out1);
}

// Round 4
// 2104.545 us; speedup vs baseline: 21.2795x; 1.1962x over previous
//
#include <hip/hip_runtime.h>

// PathEncoder: B=8, N_NODE=512, N_TOK=8, N_PATHS=256, PATH_LEN=64, VOCAB=50000, H=256
// Round 4: asm-pinned register-resident recurrent weights (defeat load sinking),
// kernel split: path scan -> (base GRU || rank GEMM) fused for overlap,
// col-pair lane mapping (packed u32 h-writes, conflict-free LDS).
//
// ws layout (bytes): identical sizes to round 3.
//   x       @ 0          4,194,304   [4096][256] f32
//   xbf     @ 4194304    2,097,152   [4096][256] bf16
//   xw3     @ 6291456   12,585,984   [4097]x1536 bf16 packed: dir*768 + w*96 + lm*6 + g*2 + n
//                                    (col = g*256 + w*32 + 2*lm + n)
//   whhp    @ 18877440     786,432   packed whh bf16 MFMA B-frags (col-pair layout)
//   wih_bt  @ 19663872     786,432   [1536][256] bf16 concat(wf_ih, wb_ih)
//   wr_bt   @ 20450304     524,288   [512][512] bf16 w_rank[:, :512]
//   rank_l  @ 20974592       2,048   [512] f32 w_rank[:, 512]
//   bias2   @ 20976640       6,144   [1536] f32 b_ih + (bhh for r,z gates)
//   keys    @ 20982784   8,404,992   [8][513][512] u32 scatter-max
//   base_v  @ 29387776   8,388,608   [8][512][512] f32
//   nx      @ 37776384 134,217,728   [131072][512] bf16
//   total ≈ 172 MB

#define HH 256
#define NNODE 512
#define PLEN 64

typedef __attribute__((ext_vector_type(8))) short short8;
typedef __attribute__((ext_vector_type(4))) float f32x4;
typedef unsigned short ushort_t;
typedef __attribute__((address_space(1))) const void* gas_t;
typedef __attribute__((address_space(3))) void* las_t;

__device__ __forceinline__ f32x4 mfma16(short8 a, short8 b, f32x4 c) {
    return __builtin_amdgcn_mfma_f32_16x16x32_bf16(a, b, c, 0, 0, 0);
}
__device__ __forceinline__ ushort_t f2bf(float f) {
    unsigned u = __float_as_uint(f);
    u += 0x7fffu + ((u >> 16) & 1u);
    return (ushort_t)(u >> 16);
}
__device__ __forceinline__ float bf2f(ushort_t s) {
    return __uint_as_float(((unsigned)s) << 16);
}
__device__ __forceinline__ float sigm(float x) {
    return __builtin_amdgcn_rcpf(1.f + __expf(-x));
}
__device__ __forceinline__ float tanh_(float x) {
    return 1.f - 2.f * __builtin_amdgcn_rcpf(__expf(2.f * x) + 1.f);
}
__device__ __forceinline__ unsigned fkey(float f) {
    unsigned u = __float_as_uint(f);
    return (u & 0x80000000u) ? ~u : (u | 0x80000000u);
}
__device__ __forceinline__ float fdec(unsigned k) {
    unsigned u = (k & 0x80000000u) ? (k ^ 0x80000000u) : ~k;
    return __uint_as_float(u);
}

// xw3 remap: original col c in [0,1536) -> packed element offset within a row.
// col within dir: g*256 + w*32 + 2*lm + n  ->  w*96 + lm*6 + g*2 + n
__device__ __forceinline__ int xw3_remap(int c) {
    const int dir = c >= 768;
    const int cd = c - dir * 768;
    const int g = cd >> 8, cc = cd & 255;
    const int w2 = cc >> 5, within = cc & 31;
    return dir * 768 + w2 * 96 + (within >> 1) * 6 + g * 2 + (within & 1);
}

// ---------------- embedding token max-pool ----------------
__global__ void k_embed(const int* __restrict__ nodes, const float* __restrict__ emb,
                        float* __restrict__ x, ushort_t* __restrict__ xbf)
{
    const int bn = blockIdx.x, h = threadIdx.x;
    const int* nd = nodes + bn * 8;
    float m = -3.4e38f;
#pragma unroll
    for (int k = 0; k < 8; ++k)
        m = fmaxf(m, emb[(size_t)nd[k] * HH + h]);
    x[(size_t)bn * HH + h] = m;
    xbf[(size_t)bn * HH + h] = f2bf(m);
}

// ---------------- pack weights ----------------
__global__ void k_pack(const float* __restrict__ wf_ih, const float* __restrict__ wf_hh,
                       const float* __restrict__ bf_ih, const float* __restrict__ bf_hh,
                       const float* __restrict__ wb_ih, const float* __restrict__ wb_hh,
                       const float* __restrict__ bb_ih, const float* __restrict__ bb_hh,
                       const float* __restrict__ w_rank,
                       ushort_t* __restrict__ whhp, ushort_t* __restrict__ wih_bt,
                       ushort_t* __restrict__ wr_bt, float* __restrict__ rank_l,
                       float* __restrict__ bias2, ushort_t* __restrict__ xw3)
{
    int i = blockIdx.x * 256 + threadIdx.x;
    if (i < 393216) {
        // chunk c = ((dir*8+w)*8+kt)*6 + g*2 + n; lane l elem e:
        // whhp <- whh[g*256 + w*32 + 2*(l&15) + n][kt*32 + (l>>4)*8 + e]
        const int e = i & 7, l = (i >> 3) & 63;
        int c = i >> 9;
        const int n = c & 1; c >>= 1;
        const int g = c % 3; c /= 3;
        const int kt = c & 7; c >>= 3;
        const int w2 = c & 7;
        const int dir = c >> 3;
        const float* whh = dir ? wb_hh : wf_hh;
        whhp[i] = f2bf(whh[(g * 256 + w2 * 32 + 2 * (l & 15) + n) * 256 +
                           kt * 32 + (l >> 4) * 8 + e]);
        return;
    }
    i -= 393216;
    if (i < 393216) {   // wih_bt [1536][256]
        const int n = i >> 8, k = i & 255;
        const float* wih = (n < 768) ? wf_ih : wb_ih;
        wih_bt[i] = f2bf(wih[(n % 768) * 256 + k]);
        return;
    }
    i -= 393216;
    if (i < 262144) { wr_bt[i] = f2bf(w_rank[(i >> 9) * 513 + (i & 511)]); return; }
    i -= 262144;
    if (i < 512) { rank_l[i] = w_rank[i * 513 + 512]; return; }
    i -= 512;
    if (i < 1536) {
        const int c = i;
        const int dir = c >= 768;
        const int cd = c - dir * 768;
        const int g = cd >> 8;
        const float bi = dir ? bb_ih[cd] : bf_ih[cd];
        const float bh = (g < 2) ? (dir ? bb_hh[cd] : bf_hh[cd]) : 0.f;
        bias2[c] = bi + bh;
        xw3[(size_t)4096 * 1536 + xw3_remap(c)] = f2bf(bi + bh);  // padding row
    }
}

// ---------------- GEMM mainloop (256 thr, 128x128, BK=64; A,Bt row-major [*][K]) ----
template<int KD>
__device__ __forceinline__ void gemm_loop(const ushort_t* __restrict__ A,
                                          const ushort_t* __restrict__ Bt,
                                          ushort_t* al, ushort_t* bl,
                                          int bm, int bn, f32x4 acc[4][4])
{
    const int tid = threadIdx.x, w = tid >> 6, l = tid & 63;
    const int lm = l & 15, lh = l >> 4;
    const int wm = w >> 1, wn = w & 1;
    const int lr = l >> 3, lc = (l & 7) * 8;
    for (int k0 = 0; k0 < KD; k0 += 64) {
#pragma unroll
        for (int i = 0; i < 4; ++i) {
            const int c = w * 4 + i;
            const ushort_t* ga = A + (size_t)(bm + c * 8 + lr) * KD + k0 + lc;
            const ushort_t* gb = Bt + (size_t)(bn + c * 8 + lr) * KD + k0 + lc;
            __builtin_amdgcn_global_load_lds((gas_t)ga, (las_t)(al + c * 512), 16, 0, 0);
            __builtin_amdgcn_global_load_lds((gas_t)gb, (las_t)(bl + c * 512), 16, 0, 0);
        }
        __syncthreads();
#pragma unroll
        for (int kt = 0; kt < 2; ++kt) {
            short8 af[4], bfr[4];
            const int ko = kt * 32 + lh * 8;
#pragma unroll
            for (int m = 0; m < 4; ++m)
                af[m] = *(const short8*)(al + (wm * 64 + m * 16 + lm) * 64 + ko);
#pragma unroll
            for (int n = 0; n < 4; ++n)
                bfr[n] = *(const short8*)(bl + (wn * 64 + n * 16 + lm) * 64 + ko);
#pragma unroll
            for (int m = 0; m < 4; ++m)
#pragma unroll
                for (int n = 0; n < 4; ++n)
                    acc[m][n] = mfma16(af[m], bfr[n], acc[m][n]);
        }
        __syncthreads();
    }
}

// ---------------- xw GEMM: [4096][256] @ [256][1536] + bias2 -> packed bf16 ----------
__global__ void __launch_bounds__(256, 2)
k_gemm_xw(const ushort_t* __restrict__ xbf, const ushort_t* __restrict__ wih_bt,
          const float* __restrict__ bias2, ushort_t* __restrict__ xw3)
{
    __shared__ __align__(16) ushort_t al[128 * 64], bl[128 * 64];
    f32x4 acc[4][4] = {};
    const int bm = blockIdx.y * 128, bn = blockIdx.x * 128;
    gemm_loop<256>(xbf, wih_bt, al, bl, bm, bn, acc);
    const int tid = threadIdx.x, w = tid >> 6, l = tid & 63;
    const int lm = l & 15, lh = l >> 4, wm = w >> 1, wn = w & 1;
#pragma unroll
    for (int m = 0; m < 4; ++m)
#pragma unroll
        for (int rr = 0; rr < 4; ++rr) {
            const int row = bm + wm * 64 + m * 16 + lh * 4 + rr;
#pragma unroll
            for (int n = 0; n < 4; ++n) {
                const int col = bn + wn * 64 + n * 16 + lm;
                xw3[(size_t)row * 1536 + xw3_remap(col)] = f2bf(acc[m][n][rr] + bias2[col]);
            }
        }
}

// ---------------- GRU step core (shared by path scan and base scan) ----------------
// Wave w owns hidden cols [w*32, w*32+32) as pairs (2*lm, 2*lm+1); 48 MFMA/step.
struct GruRegs {
    short8 Bf[8][3][2];
    float bn0, bn1;
};

__device__ __forceinline__ void load_gru_weights(const ushort_t* __restrict__ whhp,
                                                 const float* __restrict__ bhh,
                                                 int dir, int w, int l, int lm,
                                                 GruRegs& R)
{
    const ushort_t* wp = whhp + (size_t)(dir * 8 + w) * 24576 + l * 8;
#pragma unroll
    for (int kt = 0; kt < 8; ++kt)
#pragma unroll
        for (int g = 0; g < 3; ++g)
#pragma unroll
            for (int n = 0; n < 2; ++n) {
                short8 v = *(const short8*)(wp + (kt * 6 + g * 2 + n) * 512);
                asm volatile("" : "+v"(v));   // pin: forbid remat/sink into step loop
                R.Bf[kt][g][n] = v;
            }
    R.bn0 = bhh[512 + w * 32 + lm * 2];
    R.bn1 = bhh[512 + w * 32 + lm * 2 + 1];
}

// ---------------- path scan: 128 blocks x 512 thr, both dirs sequential ----------
__global__ void __launch_bounds__(512, 2)
k_scan_path(const int* __restrict__ paths, const ushort_t* __restrict__ xw3,
            const ushort_t* __restrict__ whhp,
            const float* __restrict__ bf_hh, const float* __restrict__ bb_hh,
            ushort_t* __restrict__ nx)
{
    __shared__ __align__(16) ushort_t hl[2][4096];
    __shared__ int idr[1024];
    const int tid = threadIdx.x;
    const int w = tid >> 6, l = tid & 63;
    const int lm = l & 15, lh = l >> 4;
    const int sg = blockIdx.x;

    for (int i = tid; i < 1024; i += 512) {
        const int s = sg * 16 + (i >> 6), t = i & 63;
        const int id = paths[(s << 6) + t];
        idr[i] = (id < NNODE) ? (((s >> 8) << 9) + id) : 4096;
    }

    for (int dir = 0; dir < 2; ++dir) {
        GruRegs R;
        load_gru_weights(whhp, dir ? bb_hh : bf_hh, dir, w, l, lm, R);

        __syncthreads();
        for (int i = tid; i < 4096; i += 512) hl[0][i] = 0;
        float ho[4][2] = {};
        __syncthreads();

        int cur = 0;
        for (int step = 0; step < PLEN; ++step) {
            const int t = dir ? (PLEN - 1 - step) : step;
            unsigned gr[4], gz[4], gn[4];
#pragma unroll
            for (int ri = 0; ri < 4; ++ri) {
                const int sq = lh * 4 + ri;
                const int row = idr[(sq << 6) + t];
                const unsigned* gp = (const unsigned*)((const char*)xw3 +
                    (size_t)row * 3072 + dir * 1536 + w * 192 + lm * 12);
                gr[ri] = gp[0]; gz[ri] = gp[1]; gn[ri] = gp[2];
            }
            f32x4 acc[3][2] = {};
            {
                const char* hb = (const char*)hl[cur];
#pragma unroll
                for (int kt = 0; kt < 8; ++kt) {
                    const short8 a = *(const short8*)(hb + lm * 512 +
                        ((kt * 64 + lh * 16) ^ ((lm & 7) << 4)));
#pragma unroll
                    for (int g = 0; g < 3; ++g)
#pragma unroll
                        for (int n = 0; n < 2; ++n)
                            acc[g][n] = mfma16(a, R.Bf[kt][g][n], acc[g][n]);
                }
            }
            ushort_t* hn_ = hl[cur ^ 1];
#pragma unroll
            for (int ri = 0; ri < 4; ++ri) {
                const int sq = lh * 4 + ri;
                unsigned hpack = 0;
#pragma unroll
                for (int n = 0; n < 2; ++n) {
                    const float xr = bf2f((ushort_t)(n ? (gr[ri] >> 16) : (gr[ri] & 0xffffu)));
                    const float xz = bf2f((ushort_t)(n ? (gz[ri] >> 16) : (gz[ri] & 0xffffu)));
                    const float xn = bf2f((ushort_t)(n ? (gn[ri] >> 16) : (gn[ri] & 0xffffu)));
                    const float rr = sigm(acc[0][n][ri] + xr);
                    const float zz = sigm(acc[1][n][ri] + xz);
                    const float nn = tanh_(xn + rr * (acc[2][n][ri] + (n ? R.bn1 : R.bn0)));
                    const float h = (1.f - zz) * nn + zz * ho[ri][n];
                    ho[ri][n] = h;
                    hpack |= ((unsigned)f2bf(h)) << (n * 16);
                }
                *(unsigned*)((char*)hn_ + sq * 512 +
                    ((w * 64 + lm * 4) ^ ((sq & 7) << 4))) = hpack;
                *(unsigned*)((char*)nx + (((size_t)((sg * 16 + sq) * PLEN + t)) * 512 +
                    dir * 256 + w * 32 + lm * 2) * 2) = hpack;
            }
            __syncthreads();
            cur ^= 1;
        }
    }
}

// ---------------- fused: blocks 0,1 = base GRU (512 steps); 2.. = rank GEMM ----------
__global__ void __launch_bounds__(512, 2)
k_rank_base(const int* __restrict__ paths, const ushort_t* __restrict__ xw3,
            const ushort_t* __restrict__ whhp,
            const float* __restrict__ bf_hh, const float* __restrict__ bb_hh,
            const ushort_t* __restrict__ nx, const ushort_t* __restrict__ wr_bt,
            const float* __restrict__ b_rank, const float* __restrict__ rank_l,
            float* __restrict__ base_v, unsigned* __restrict__ keys)
{
    __shared__ __align__(16) ushort_t smem[16384];  // 32 KB
    const int tid = threadIdx.x;
    const int w = tid >> 6, l = tid & 63;
    const int lm = l & 15, lh = l >> 4;

    if (blockIdx.x < 2) {
        // ---- base bidirectional GRU: one block per dir, M-tile 16 (8 real batches) ----
        ushort_t* hl0 = smem;
        ushort_t* hl1 = smem + 4096;
        const int dir = blockIdx.x;
        GruRegs R;
        load_gru_weights(whhp, dir ? bb_hh : bf_hh, dir, w, l, lm, R);

        for (int i = tid; i < 4096; i += 512) hl0[i] = 0;
        float ho[4][2] = {};
        __syncthreads();

        int cur = 0;
        for (int step = 0; step < NNODE; ++step) {
            const int t = dir ? (NNODE - 1 - step) : step;
            unsigned gr[4], gz[4], gn[4];
#pragma unroll
            for (int ri = 0; ri < 4; ++ri) {
                const int sq = lh * 4 + ri;
                const int row = (sq < 8) ? ((sq << 9) + t) : 4096;
                const unsigned* gp = (const unsigned*)((const char*)xw3 +
                    (size_t)row * 3072 + dir * 1536 + w * 192 + lm * 12);
                gr[ri] = gp[0]; gz[ri] = gp[1]; gn[ri] = gp[2];
            }
            f32x4 acc[3][2] = {};
            {
                const char* hb = (const char*)(cur ? hl1 : hl0);
#pragma unroll
                for (int kt = 0; kt < 8; ++kt) {
                    const short8 a = *(const short8*)(hb + lm * 512 +
                        ((kt * 64 + lh * 16) ^ ((lm & 7) << 4)));
#pragma unroll
                    for (int g = 0; g < 3; ++g)
#pragma unroll
                        for (int n = 0; n < 2; ++n)
                            acc[g][n] = mfma16(a, R.Bf[kt][g][n], acc[g][n]);
                }
            }
            ushort_t* hn_ = cur ? hl0 : hl1;
#pragma unroll
            for (int ri = 0; ri < 4; ++ri) {
                const int sq = lh * 4 + ri;
                unsigned hpack = 0;
                float hp0 = 0.f, hp1 = 0.f;
#pragma unroll
                for (int n = 0; n < 2; ++n) {
                    const float xr = bf2f((ushort_t)(n ? (gr[ri] >> 16) : (gr[ri] & 0xffffu)));
                    const float xz = bf2f((ushort_t)(n ? (gz[ri] >> 16) : (gz[ri] & 0xffffu)));
                    const float xn = bf2f((ushort_t)(n ? (gn[ri] >> 16) : (gn[ri] & 0xffffu)));
                    const float rr = sigm(acc[0][n][ri] + xr);
                    const float zz = sigm(acc[1][n][ri] + xz);
                    const float nn = tanh_(xn + rr * (acc[2][n][ri] + (n ? R.bn1 : R.bn0)));
                    const float h = (1.f - zz) * nn + zz * ho[ri][n];
                    ho[ri][n] = h;
                    hpack |= ((unsigned)f2bf(h)) << (n * 16);
                    if (n) hp1 = h; else hp0 = h;
                }
                *(unsigned*)((char*)hn_ + sq * 512 +
                    ((w * 64 + lm * 4) ^ ((sq & 7) << 4))) = hpack;
                if (sq < 8)
                    *(float2*)(base_v + ((size_t)(sq * NNODE + t)) * 512 +
                               dir * 256 + w * 32 + lm * 2) = make_float2(hp0, hp1);
            }
            __syncthreads();
            cur ^= 1;
        }
        return;
    }

    // ---- rank GEMM: one 128x128 tile per block, K=512, swizzled LDS ----
    ushort_t* al = smem;
    ushort_t* bl = smem + 8192;
    const int rb = blockIdx.x - 2;
    const int mt = rb >> 2, ntile = rb & 3;
    const size_t ar0 = (size_t)mt * 128;
    const int n0 = ntile * 128;
    const int wm = w >> 2, wn = w & 3;   // wave tile 64x32
    f32x4 racc[4][2] = {};
    for (int k0 = 0; k0 < 512; k0 += 64) {
#pragma unroll
        for (int i = 0; i < 2; ++i) {
            const int c = w * 128 + i * 64 + l;
            const int row = c >> 3, j = c & 7;
            const int jp = j ^ (row & 7);   // pre-swizzled source (both-sides rule)
            __builtin_amdgcn_global_load_lds(
                (gas_t)(nx + (ar0 + row) * 512 + k0 + jp * 8),
                (las_t)(al + c * 8), 16, 0, 0);
            __builtin_amdgcn_global_load_lds(
                (gas_t)(wr_bt + (size_t)(n0 + row) * 512 + k0 + jp * 8),
                (las_t)(bl + c * 8), 16, 0, 0);
        }
        __syncthreads();
#pragma unroll
        for (int kt = 0; kt < 2; ++kt) {
            short8 av[4], bv[2];
#pragma unroll
            for (int m = 0; m < 4; ++m) {
                const int r = wm * 64 + m * 16 + lm;
                av[m] = *(const short8*)((const char*)al + r * 128 +
                        ((kt * 64 + lh * 16) ^ ((r & 7) << 4)));
            }
#pragma unroll
            for (int n = 0; n < 2; ++n) {
                const int r = wn * 32 + n * 16 + lm;
                bv[n] = *(const short8*)((const char*)bl + r * 128 +
                        ((kt * 64 + lh * 16) ^ ((r & 7) << 4)));
            }
#pragma unroll
            for (int m = 0; m < 4; ++m)
#pragma unroll
                for (int n = 0; n < 2; ++n)
                    racc[m][n] = mfma16(av[m], bv[n], racc[m][n]);
        }
        __syncthreads();
    }
#pragma unroll
    for (int m = 0; m < 4; ++m)
#pragma unroll
        for (int rr = 0; rr < 4; ++rr) {
            const size_t grow = ar0 + wm * 64 + m * 16 + lh * 4 + rr;
            const int id = paths[grow];
            const float rv = __builtin_amdgcn_rcpf((float)(((grow >> 6) & 255) + 1));
            unsigned* kp = keys + (((grow >> 14) * 513 + id) << 9);
#pragma unroll
            for (int n = 0; n < 2; ++n) {
                const int col = n0 + wn * 32 + n * 16 + lm;
                const float v = racc[m][n][rr] + b_rank[col] + rank_l[col] * rv;
                if (id < NNODE) {
                    const unsigned key = fkey(v);
                    if (key > kp[col]) atomicMax(kp + col, key);
                }
            }
        }
}

// ---------------- merge: v = has ? vmax : transit(x);  all_v = base_v + v ----------------
__global__ void k_merge(const unsigned* __restrict__ keys, const float* __restrict__ base_v,
                        const float* __restrict__ x, const float* __restrict__ w_transit,
                        const float* __restrict__ b_transit, float* __restrict__ out0)
{
    const int blk = blockIdx.x;
    const int b = blk >> 9, n = blk & 511;
    const int tid = threadIdx.x;
#pragma unroll
    for (int h = 0; h < 2; ++h) {
        const int o = tid + h * 256;
        const unsigned k = keys[((size_t)(b * 513 + n)) * 512 + o];
        float v;
        if (k) {
            v = fdec(k);
        } else {
            float a = b_transit[o];
            const float* wt = w_transit + o * HH;
            const float* xr = x + ((size_t)(b * NNODE + n)) * HH;
            for (int i = 0; i < HH; ++i) a += xr[i] * wt[i];
            v = a;
        }
        const size_t oi = ((size_t)(b * NNODE + n)) * 512 + o;
        out0[oi] = base_v[oi] + v;
    }
}

// ---------------- last_state: rowmax over nodes, then @ w_h.T + b_h ----------------
__global__ void k_last(const float* __restrict__ out0, const float* __restrict__ w_h,
                       const float* __restrict__ b_h, float* __restrict__ out1)
{
    __shared__ float m[512];
    const int b = blockIdx.x, tid = threadIdx.x;
#pragma unroll
    for (int h = 0; h < 2; ++h) {
        const int o = tid + h * 256;
        float mm = -3.4e38f;
        for (int n = 0; n < NNODE; ++n)
            mm = fmaxf(mm, out0[((size_t)(b * NNODE + n)) * 512 + o]);
        m[o] = mm;
    }
    __syncthreads();
    float a = b_h[tid];
    const float* wr = w_h + tid * 512;
    for (int j = 0; j < 512; ++j) a += m[j] * wr[j];
    out1[b * HH + tid] = a;
}

extern "C" void kernel_launch(void* const* d_in, const int* in_sizes, int n_in,
                              void* d_out, int out_size, void* d_ws, size_t ws_size,
                              hipStream_t stream)
{
    (void)in_sizes; (void)n_in; (void)out_size; (void)ws_size;
    const int* nodes = (const int*)d_in[0];
    const int* paths = (const int*)d_in[1];
    const float* emb = (const float*)d_in[2];
    const float* wf_ih = (const float*)d_in[3];
    const float* wf_hh = (const float*)d_in[4];
    const float* bf_ih = (const float*)d_in[5];
    const float* bf_hh = (const float*)d_in[6];
    const float* wb_ih = (const float*)d_in[7];
    const float* wb_hh = (const float*)d_in[8];
    const float* bb_ih = (const float*)d_in[9];
    const float* bb_hh = (const float*)d_in[10];
    const float* w_transit = (const float*)d_in[11];
    const float* b_transit = (const float*)d_in[12];
    const float* w_rank = (const float*)d_in[13];
    const float* b_rank = (const float*)d_in[14];
    const float* w_h = (const float*)d_in[15];
    const float* b_h = (const float*)d_in[16];

    char* ws = (char*)d_ws;
    float* x = (float*)(ws);
    ushort_t* xbf = (ushort_t*)(ws + 4194304);
    ushort_t* xw3 = (ushort_t*)(ws + 6291456);
    ushort_t* whhp = (ushort_t*)(ws + 18877440);
    ushort_t* wih_bt = (ushort_t*)(ws + 19663872);
    ushort_t* wr_bt = (ushort_t*)(ws + 20450304);
    float* rank_l = (float*)(ws + 20974592);
    float* bias2 = (float*)(ws + 20976640);
    unsigned* keys = (unsigned*)(ws + 20982784);
    float* base_v = (float*)(ws + 29387776);
    ushort_t* nx = (ushort_t*)(ws + 37776384);

    float* out0 = (float*)d_out;
    float* out1 = out0 + 2097152;

    hipMemsetAsync(keys, 0, 8404992, stream);
    k_embed<<<4096, 256, 0, stream>>>(nodes, emb, x, xbf);
    k_pack<<<4104, 256, 0, stream>>>(wf_ih, wf_hh, bf_ih, bf_hh, wb_ih, wb_hh,
                                     bb_ih, bb_hh, w_rank,
                                     whhp, wih_bt, wr_bt, rank_l, bias2, xw3);
    k_gemm_xw<<<dim3(12, 32), 256, 0, stream>>>(xbf, wih_bt, bias2, xw3);
    k_scan_path<<<128, 512, 0, stream>>>(paths, xw3, whhp, bf_hh, bb_hh, nx);
    k_rank_base<<<4098, 512, 0, stream>>>(paths, xw3, whhp, bf_hh, bb_hh, nx,
                                          wr_bt, b_rank, rank_l, base_v, keys);
    k_merge<<<4096, 256, 0, stream>>>(keys, base_v, x, w_transit, b_transit, out0);
    k_last<<<8, 256, 0, stream>>>(out0, w_h, b_h, out1);
}

// Round 5
// 2013.674 us; speedup vs baseline: 22.2398x; 1.0451x over previous
//
#include <hip/hip_runtime.h>

// PathEncoder: B=8, N_NODE=512, N_TOK=8, N_PATHS=256, PATH_LEN=64, VOCAB=50000, H=256
// Round 5: Bf weights pinned into AGPRs ("+a" asm pin; class-segregated so the
// allocator spills scalars, not the weight array); h_old re-read from LDS (bf16)
// to cut 8 regs of liveness; base+path+rank re-fused into one 130-block kernel.
//
// ws layout (bytes): identical to round 4.
//   x       @ 0          4,194,304   [4096][256] f32
//   xbf     @ 4194304    2,097,152   [4096][256] bf16
//   xw3     @ 6291456   12,585,984   [4097]x1536 bf16 packed: dir*768 + w*96 + lm*6 + g*2 + n
//   whhp    @ 18877440     786,432   packed whh bf16 MFMA B-frags (col-pair layout)
//   wih_bt  @ 19663872     786,432   [1536][256] bf16 concat(wf_ih, wb_ih)
//   wr_bt   @ 20450304     524,288   [512][512] bf16 w_rank[:, :512]
//   rank_l  @ 20974592       2,048   [512] f32 w_rank[:, 512]
//   bias2   @ 20976640       6,144   [1536] f32 b_ih + (bhh for r,z gates)
//   keys    @ 20982784   8,404,992   [8][513][512] u32 scatter-max
//   base_v  @ 29387776   8,388,608   [8][512][512] f32
//   nx      @ 37776384 134,217,728   [131072][512] bf16
//   total ≈ 172 MB

#define HH 256
#define NNODE 512
#define PLEN 64

typedef __attribute__((ext_vector_type(8))) short short8;
typedef __attribute__((ext_vector_type(4))) float f32x4;
typedef unsigned short ushort_t;
typedef __attribute__((address_space(1))) const void* gas_t;
typedef __attribute__((address_space(3))) void* las_t;

__device__ __forceinline__ f32x4 mfma16(short8 a, short8 b, f32x4 c) {
    return __builtin_amdgcn_mfma_f32_16x16x32_bf16(a, b, c, 0, 0, 0);
}
__device__ __forceinline__ ushort_t f2bf(float f) {
    unsigned u = __float_as_uint(f);
    u += 0x7fffu + ((u >> 16) & 1u);
    return (ushort_t)(u >> 16);
}
__device__ __forceinline__ float bf2f(ushort_t s) {
    return __uint_as_float(((unsigned)s) << 16);
}
__device__ __forceinline__ float sigm(float x) {
    return __builtin_amdgcn_rcpf(1.f + __expf(-x));
}
__device__ __forceinline__ float tanh_(float x) {
    return 1.f - 2.f * __builtin_amdgcn_rcpf(__expf(2.f * x) + 1.f);
}
__device__ __forceinline__ unsigned fkey(float f) {
    unsigned u = __float_as_uint(f);
    return (u & 0x80000000u) ? ~u : (u | 0x80000000u);
}
__device__ __forceinline__ float fdec(unsigned k) {
    unsigned u = (k & 0x80000000u) ? (k ^ 0x80000000u) : ~k;
    return __uint_as_float(u);
}

// xw3 remap: original col c in [0,1536) -> packed element offset within a row.
// col within dir: g*256 + w*32 + 2*lm + n  ->  w*96 + lm*6 + g*2 + n
__device__ __forceinline__ int xw3_remap(int c) {
    const int dir = c >= 768;
    const int cd = c - dir * 768;
    const int g = cd >> 8, cc = cd & 255;
    const int w2 = cc >> 5, within = cc & 31;
    return dir * 768 + w2 * 96 + (within >> 1) * 6 + g * 2 + (within & 1);
}

// ---------------- embedding token max-pool ----------------
__global__ void k_embed(const int* __restrict__ nodes, const float* __restrict__ emb,
                        float* __restrict__ x, ushort_t* __restrict__ xbf)
{
    const int bn = blockIdx.x, h = threadIdx.x;
    const int* nd = nodes + bn * 8;
    float m = -3.4e38f;
#pragma unroll
    for (int k = 0; k < 8; ++k)
        m = fmaxf(m, emb[(size_t)nd[k] * HH + h]);
    x[(size_t)bn * HH + h] = m;
    xbf[(size_t)bn * HH + h] = f2bf(m);
}

// ---------------- pack weights ----------------
__global__ void k_pack(const float* __restrict__ wf_ih, const float* __restrict__ wf_hh,
                       const float* __restrict__ bf_ih, const float* __restrict__ bf_hh,
                       const float* __restrict__ wb_ih, const float* __restrict__ wb_hh,
                       const float* __restrict__ bb_ih, const float* __restrict__ bb_hh,
                       const float* __restrict__ w_rank,
                       ushort_t* __restrict__ whhp, ushort_t* __restrict__ wih_bt,
                       ushort_t* __restrict__ wr_bt, float* __restrict__ rank_l,
                       float* __restrict__ bias2, ushort_t* __restrict__ xw3)
{
    int i = blockIdx.x * 256 + threadIdx.x;
    if (i < 393216) {
        // chunk c = ((dir*8+w)*8+kt)*6 + g*2 + n; lane l elem e:
        // whhp <- whh[g*256 + w*32 + 2*(l&15) + n][kt*32 + (l>>4)*8 + e]
        const int e = i & 7, l = (i >> 3) & 63;
        int c = i >> 9;
        const int n = c & 1; c >>= 1;
        const int g = c % 3; c /= 3;
        const int kt = c & 7; c >>= 3;
        const int w2 = c & 7;
        const int dir = c >> 3;
        const float* whh = dir ? wb_hh : wf_hh;
        whhp[i] = f2bf(whh[(g * 256 + w2 * 32 + 2 * (l & 15) + n) * 256 +
                           kt * 32 + (l >> 4) * 8 + e]);
        return;
    }
    i -= 393216;
    if (i < 393216) {   // wih_bt [1536][256]
        const int n = i >> 8, k = i & 255;
        const float* wih = (n < 768) ? wf_ih : wb_ih;
        wih_bt[i] = f2bf(wih[(n % 768) * 256 + k]);
        return;
    }
    i -= 393216;
    if (i < 262144) { wr_bt[i] = f2bf(w_rank[(i >> 9) * 513 + (i & 511)]); return; }
    i -= 262144;
    if (i < 512) { rank_l[i] = w_rank[i * 513 + 512]; return; }
    i -= 512;
    if (i < 1536) {
        const int c = i;
        const int dir = c >= 768;
        const int cd = c - dir * 768;
        const int g = cd >> 8;
        const float bi = dir ? bb_ih[cd] : bf_ih[cd];
        const float bh = (g < 2) ? (dir ? bb_hh[cd] : bf_hh[cd]) : 0.f;
        bias2[c] = bi + bh;
        xw3[(size_t)4096 * 1536 + xw3_remap(c)] = f2bf(bi + bh);  // padding row
    }
}

// ---------------- GEMM mainloop (256 thr, 128x128, BK=64; A,Bt row-major [*][K]) ----
template<int KD>
__device__ __forceinline__ void gemm_loop(const ushort_t* __restrict__ A,
                                          const ushort_t* __restrict__ Bt,
                                          ushort_t* al, ushort_t* bl,
                                          int bm, int bn, f32x4 acc[4][4])
{
    const int tid = threadIdx.x, w = tid >> 6, l = tid & 63;
    const int lm = l & 15, lh = l >> 4;
    const int wm = w >> 1, wn = w & 1;
    const int lr = l >> 3, lc = (l & 7) * 8;
    for (int k0 = 0; k0 < KD; k0 += 64) {
#pragma unroll
        for (int i = 0; i < 4; ++i) {
            const int c = w * 4 + i;
            const ushort_t* ga = A + (size_t)(bm + c * 8 + lr) * KD + k0 + lc;
            const ushort_t* gb = Bt + (size_t)(bn + c * 8 + lr) * KD + k0 + lc;
            __builtin_amdgcn_global_load_lds((gas_t)ga, (las_t)(al + c * 512), 16, 0, 0);
            __builtin_amdgcn_global_load_lds((gas_t)gb, (las_t)(bl + c * 512), 16, 0, 0);
        }
        __syncthreads();
#pragma unroll
        for (int kt = 0; kt < 2; ++kt) {
            short8 af[4], bfr[4];
            const int ko = kt * 32 + lh * 8;
#pragma unroll
            for (int m = 0; m < 4; ++m)
                af[m] = *(const short8*)(al + (wm * 64 + m * 16 + lm) * 64 + ko);
#pragma unroll
            for (int n = 0; n < 4; ++n)
                bfr[n] = *(const short8*)(bl + (wn * 64 + n * 16 + lm) * 64 + ko);
#pragma unroll
            for (int m = 0; m < 4; ++m)
#pragma unroll
                for (int n = 0; n < 4; ++n)
                    acc[m][n] = mfma16(af[m], bfr[n], acc[m][n]);
        }
        __syncthreads();
    }
}

// ---------------- xw GEMM: [4096][256] @ [256][1536] + bias2 -> packed bf16 ----------
__global__ void __launch_bounds__(256, 2)
k_gemm_xw(const ushort_t* __restrict__ xbf, const ushort_t* __restrict__ wih_bt,
          const float* __restrict__ bias2, ushort_t* __restrict__ xw3)
{
    __shared__ __align__(16) ushort_t al[128 * 64], bl[128 * 64];
    f32x4 acc[4][4] = {};
    const int bm = blockIdx.y * 128, bn = blockIdx.x * 128;
    gemm_loop<256>(xbf, wih_bt, al, bl, bm, bn, acc);
    const int tid = threadIdx.x, w = tid >> 6, l = tid & 63;
    const int lm = l & 15, lh = l >> 4, wm = w >> 1, wn = w & 1;
#pragma unroll
    for (int m = 0; m < 4; ++m)
#pragma unroll
        for (int rr = 0; rr < 4; ++rr) {
            const int row = bm + wm * 64 + m * 16 + lh * 4 + rr;
#pragma unroll
            for (int n = 0; n < 4; ++n) {
                const int col = bn + wn * 64 + n * 16 + lm;
                xw3[(size_t)row * 1536 + xw3_remap(col)] = f2bf(acc[m][n][rr] + bias2[col]);
            }
        }
}

// ---------------- GRU scan core ----------------
// 512 thr = 8 waves; wave w owns hidden cols [w*32, w*32+32) as pairs (2lm, 2lm+1)
// across all 3 gates. Bf = 48 short8 pinned in AGPRs; h carried in LDS (bf16).
template<bool IS_BASE>
__device__ __forceinline__ void scan_run(int dir, int sg, int tid,
    const ushort_t* __restrict__ xw3, const ushort_t* __restrict__ whhp,
    const float* __restrict__ bhh, ushort_t (*hl)[4096], const int* idr,
    ushort_t* __restrict__ nx, float* __restrict__ base_v)
{
    const int w = tid >> 6, l = tid & 63;
    const int lm = l & 15, lh = l >> 4;
    const int nsteps = IS_BASE ? NNODE : PLEN;

    short8 Bf[8][3][2];
    {
        const ushort_t* wp = whhp + (size_t)(dir * 8 + w) * 24576 + l * 8;
#pragma unroll
        for (int kt = 0; kt < 8; ++kt)
#pragma unroll
            for (int g = 0; g < 3; ++g)
#pragma unroll
                for (int n = 0; n < 2; ++n) {
                    short8 v = *(const short8*)(wp + (kt * 6 + g * 2 + n) * 512);
                    asm volatile("" : "+a"(v));   // pin into AGPR class, no remat/spill-to-scratch
                    Bf[kt][g][n] = v;
                }
    }
    const float bn0 = bhh[512 + w * 32 + lm * 2];
    const float bn1 = bhh[512 + w * 32 + lm * 2 + 1];

    __syncthreads();
    for (int i = tid; i < 4096; i += 512) hl[0][i] = 0;
    __syncthreads();

    int cur = 0;
    for (int step = 0; step < nsteps; ++step) {
        const int t = dir ? (nsteps - 1 - step) : step;
        // xw gather: 12B per (lane, ri) = {r,z,n} x col-pair (hidden under MFMA)
        uint3 gv[4];
#pragma unroll
        for (int ri = 0; ri < 4; ++ri) {
            const int sq = lh * 4 + ri;
            const int row = IS_BASE ? ((sq < 8) ? ((sq << 9) + t) : 4096)
                                    : idr[(sq << 6) + t];
            gv[ri] = *(const uint3*)((const char*)xw3 +
                (size_t)row * 3072 + dir * 1536 + w * 192 + lm * 12);
        }
        // gates = h @ whh^T: M=16 seqs, own 96 gate-cols, K=256
        f32x4 acc[3][2] = {};
        const char* hb = (const char*)hl[cur];
#pragma unroll
        for (int kt = 0; kt < 8; ++kt) {
            const short8 a = *(const short8*)(hb + lm * 512 +
                ((kt * 64 + lh * 16) ^ ((lm & 7) << 4)));
#pragma unroll
            for (int g = 0; g < 3; ++g)
#pragma unroll
                for (int n = 0; n < 2; ++n)
                    acc[g][n] = mfma16(a, Bf[kt][g][n], acc[g][n]);
        }
        ushort_t* hn_ = hl[cur ^ 1];
#pragma unroll
        for (int ri = 0; ri < 4; ++ri) {
            const int sq = lh * 4 + ri;
            // h_old read back from LDS (bf16) instead of f32 register carry
            const unsigned hv = *(const unsigned*)(hb + sq * 512 +
                ((w * 64 + lm * 4) ^ ((sq & 7) << 4)));
            unsigned hpack = 0;
            float hs0 = 0.f, hs1 = 0.f;
#pragma unroll
            for (int n = 0; n < 2; ++n) {
                const float xr = bf2f((ushort_t)(n ? (gv[ri].x >> 16) : (gv[ri].x & 0xffffu)));
                const float xz = bf2f((ushort_t)(n ? (gv[ri].y >> 16) : (gv[ri].y & 0xffffu)));
                const float xn = bf2f((ushort_t)(n ? (gv[ri].z >> 16) : (gv[ri].z & 0xffffu)));
                const float hov = bf2f((ushort_t)(n ? (hv >> 16) : (hv & 0xffffu)));
                const float rr = sigm(acc[0][n][ri] + xr);
                const float zz = sigm(acc[1][n][ri] + xz);
                const float nn = tanh_(xn + rr * (acc[2][n][ri] + (n ? bn1 : bn0)));
                const float h = (1.f - zz) * nn + zz * hov;
                if (n) hs1 = h; else hs0 = h;
                hpack |= ((unsigned)f2bf(h)) << (n * 16);
            }
            *(unsigned*)((char*)hn_ + sq * 512 + ((w * 64 + lm * 4) ^ ((sq & 7) << 4))) = hpack;
            if (IS_BASE) {
                if (sq < 8)
                    *(float2*)(base_v + ((size_t)(sq * NNODE + t)) * 512 +
                               dir * 256 + w * 32 + lm * 2) = make_float2(hs0, hs1);
            } else {
                *(unsigned*)((char*)nx + (((size_t)((sg * 16 + sq) * PLEN + t)) * 512 +
                    dir * 256 + w * 32 + lm * 2) * 2) = hpack;
            }
        }
        __syncthreads();
        cur ^= 1;
    }
}

// ---------------- fused: blocks 0,1 = base GRU; 2..129 = path scan + rank GEMM ----
__global__ void __launch_bounds__(512, 2)
k_scan(const int* __restrict__ paths, const ushort_t* __restrict__ xw3,
       const ushort_t* __restrict__ whhp,
       const float* __restrict__ bf_hh, const float* __restrict__ bb_hh,
       const ushort_t* __restrict__ wr_bt, const float* __restrict__ b_rank,
       const float* __restrict__ rank_l,
       ushort_t* __restrict__ nx, float* __restrict__ base_v,
       unsigned* __restrict__ keys)
{
    __shared__ __align__(16) ushort_t hl[2][4096];
    __shared__ __align__(16) ushort_t al[8192], bl[8192];
    __shared__ int idr[1024];
    const int tid = threadIdx.x;
    const int w = tid >> 6, l = tid & 63;
    const int lm = l & 15, lh = l >> 4;

    if (blockIdx.x < 2) {
        scan_run<true>((int)blockIdx.x, 0, tid, xw3, whhp,
                       blockIdx.x ? bb_hh : bf_hh, hl, nullptr, nx, base_v);
        return;
    }
    const int sg = (int)blockIdx.x - 2;
    for (int i = tid; i < 1024; i += 512) {
        const int s = sg * 16 + (i >> 6), t = i & 63;
        const int id = paths[(s << 6) + t];
        idr[i] = (id < NNODE) ? (((s >> 8) << 9) + id) : 4096;
    }
    scan_run<false>(0, sg, tid, xw3, whhp, bf_hh, hl, idr, nx, base_v);
    scan_run<false>(1, sg, tid, xw3, whhp, bb_hh, hl, idr, nx, base_v);

    // ---- rank phase: own 1024 nx rows @ wr^T, 32 jobs of 128x128 tiles, K=512 ----
    __threadfence_block();
    __syncthreads();
    const int wm = w >> 2, wn = w & 3;   // wave tile 64x32
#pragma unroll 1
    for (int job = 0; job < 32; ++job) {
        const int mt = job >> 2, ntile = job & 3;
        const size_t ar0 = (size_t)sg * 1024 + mt * 128;
        const int n0 = ntile * 128;
        f32x4 racc[4][2] = {};
        for (int k0 = 0; k0 < 512; k0 += 64) {
#pragma unroll
            for (int i = 0; i < 2; ++i) {
                const int c = w * 128 + i * 64 + l;
                const int row = c >> 3, j = c & 7;
                const int jp = j ^ (row & 7);   // pre-swizzled source (both-sides rule)
                __builtin_amdgcn_global_load_lds(
                    (gas_t)(nx + (ar0 + row) * 512 + k0 + jp * 8),
                    (las_t)(al + c * 8), 16, 0, 0);
                __builtin_amdgcn_global_load_lds(
                    (gas_t)(wr_bt + (size_t)(n0 + row) * 512 + k0 + jp * 8),
                    (las_t)(bl + c * 8), 16, 0, 0);
            }
            __syncthreads();
#pragma unroll
            for (int kt = 0; kt < 2; ++kt) {
                short8 av[4], bv[2];
#pragma unroll
                for (int m = 0; m < 4; ++m) {
                    const int r = wm * 64 + m * 16 + lm;
                    av[m] = *(const short8*)((const char*)al + r * 128 +
                            ((kt * 64 + lh * 16) ^ ((r & 7) << 4)));
                }
#pragma unroll
                for (int n = 0; n < 2; ++n) {
                    const int r = wn * 32 + n * 16 + lm;
                    bv[n] = *(const short8*)((const char*)bl + r * 128 +
                            ((kt * 64 + lh * 16) ^ ((r & 7) << 4)));
                }
#pragma unroll
                for (int m = 0; m < 4; ++m)
#pragma unroll
                    for (int n = 0; n < 2; ++n)
                        racc[m][n] = mfma16(av[m], bv[n], racc[m][n]);
            }
            __syncthreads();
        }
#pragma unroll
        for (int m = 0; m < 4; ++m)
#pragma unroll
            for (int rr = 0; rr < 4; ++rr) {
                const size_t grow = ar0 + wm * 64 + m * 16 + lh * 4 + rr;
                const int id = paths[grow];
                const float rv = __builtin_amdgcn_rcpf((float)(((grow >> 6) & 255) + 1));
                unsigned* kp = keys + (((grow >> 14) * 513 + id) << 9);
#pragma unroll
                for (int n = 0; n < 2; ++n) {
                    const int col = n0 + wn * 32 + n * 16 + lm;
                    const float v = racc[m][n][rr] + b_rank[col] + rank_l[col] * rv;
                    if (id < NNODE) {
                        const unsigned key = fkey(v);
                        if (key > kp[col]) atomicMax(kp + col, key);
                    }
                }
            }
    }
}

// ---------------- merge: v = has ? vmax : transit(x);  all_v = base_v + v ----------------
__global__ void k_merge(const unsigned* __restrict__ keys, const float* __restrict__ base_v,
                        const float* __restrict__ x, const float* __restrict__ w_transit,
                        const float* __restrict__ b_transit, float* __restrict__ out0)
{
    const int blk = blockIdx.x;
    const int b = blk >> 9, n = blk & 511;
    const int tid = threadIdx.x;
#pragma unroll
    for (int h = 0; h < 2; ++h) {
        const int o = tid + h * 256;
        const unsigned k = keys[((size_t)(b * 513 + n)) * 512 + o];
        float v;
        if (k) {
            v = fdec(k);
        } else {
            float a = b_transit[o];
            const float* wt = w_transit + o * HH;
            const float* xr = x + ((size_t)(b * NNODE + n)) * HH;
            for (int i = 0; i < HH; ++i) a += xr[i] * wt[i];
            v = a;
        }
        const size_t oi = ((size_t)(b * NNODE + n)) * 512 + o;
        out0[oi] = base_v[oi] + v;
    }
}

// ---------------- last_state: rowmax over nodes, then @ w_h.T + b_h ----------------
__global__ void k_last(const float* __restrict__ out0, const float* __restrict__ w_h,
                       const float* __restrict__ b_h, float* __restrict__ out1)
{
    __shared__ float m[512];
    const int b = blockIdx.x, tid = threadIdx.x;
#pragma unroll
    for (int h = 0; h < 2; ++h) {
        const int o = tid + h * 256;
        float mm = -3.4e38f;
        for (int n = 0; n < NNODE; ++n)
            mm = fmaxf(mm, out0[((size_t)(b * NNODE + n)) * 512 + o]);
        m[o] = mm;
    }
    __syncthreads();
    float a = b_h[tid];
    const float* wr = w_h + tid * 512;
    for (int j = 0; j < 512; ++j) a += m[j] * wr[j];
    out1[b * HH + tid] = a;
}

extern "C" void kernel_launch(void* const* d_in, const int* in_sizes, int n_in,
                              void* d_out, int out_size, void* d_ws, size_t ws_size,
                              hipStream_t stream)
{
    (void)in_sizes; (void)n_in; (void)out_size; (void)ws_size;
    const int* nodes = (const int*)d_in[0];
    const int* paths = (const int*)d_in[1];
    const float* emb = (const float*)d_in[2];
    const float* wf_ih = (const float*)d_in[3];
    const float* wf_hh = (const float*)d_in[4];
    const float* bf_ih = (const float*)d_in[5];
    const float* bf_hh = (const float*)d_in[6];
    const float* wb_ih = (const float*)d_in[7];
    const float* wb_hh = (const float*)d_in[8];
    const float* bb_ih = (const float*)d_in[9];
    const float* bb_hh = (const float*)d_in[10];
    const float* w_transit = (const float*)d_in[11];
    const float* b_transit = (const float*)d_in[12];
    const float* w_rank = (const float*)d_in[13];
    const float* b_rank = (const float*)d_in[14];
    const float* w_h = (const float*)d_in[15];
    const float* b_h = (const float*)d_in[16];

    char* ws = (char*)d_ws;
    float* x = (float*)(ws);
    ushort_t* xbf = (ushort_t*)(ws + 4194304);
    ushort_t* xw3 = (ushort_t*)(ws + 6291456);
    ushort_t* whhp = (ushort_t*)(ws + 18877440);
    ushort_t* wih_bt = (ushort_t*)(ws + 19663872);
    ushort_t* wr_bt = (ushort_t*)(ws + 20450304);
    float* rank_l = (float*)(ws + 20974592);
    float* bias2 = (float*)(ws + 20976640);
    unsigned* keys = (unsigned*)(ws + 20982784);
    float* base_v = (float*)(ws + 29387776);
    ushort_t* nx = (ushort_t*)(ws + 37776384);

    float* out0 = (float*)d_out;
    float* out1 = out0 + 2097152;

    hipMemsetAsync(keys, 0, 8404992, stream);
    k_embed<<<4096, 256, 0, stream>>>(nodes, emb, x, xbf);
    k_pack<<<4104, 256, 0, stream>>>(wf_ih, wf_hh, bf_ih, bf_hh, wb_ih, wb_hh,
                                     bb_ih, bb_hh, w_rank,
                                     whhp, wih_bt, wr_bt, rank_l, bias2, xw3);
    k_gemm_xw<<<dim3(12, 32), 256, 0, stream>>>(xbf, wih_bt, bias2, xw3);
    k_scan<<<130, 512, 0, stream>>>(paths, xw3, whhp, bf_hh, bb_hh, wr_bt,
                                    b_rank, rank_l, nx, base_v, keys);
    k_merge<<<4096, 256, 0, stream>>>(keys, base_v, x, w_transit, b_transit, out0);
    k_last<<<8, 256, 0, stream>>>(out0, w_h, b_h, out1);
}

// Round 6
// 2011.392 us; speedup vs baseline: 22.2650x; 1.0011x over previous
//
#include <hip/hip_runtime.h>

// PathEncoder: B=8, N_NODE=512, N_TOK=8, N_PATHS=256, PATH_LEN=64, VOCAB=50000, H=256
// Round 6: r5 + amdgpu_waves_per_eu(2,2) on k_scan. The allocator's default
// 4-waves/EU target (128 regs) was spilling the 192-reg pinned Bf array to
// scratch -> 384KB/block/step L2 re-reads. Forcing target occupancy to
// 2 waves/EU (256-reg budget) lets the AGPR-pinned weights stay resident.
//
// ws layout (bytes): identical to round 5.
//   x       @ 0          4,194,304   [4096][256] f32
//   xbf     @ 4194304    2,097,152   [4096][256] bf16
//   xw3     @ 6291456   12,585,984   [4097]x1536 bf16 packed: dir*768 + w*96 + lm*6 + g*2 + n
//   whhp    @ 18877440     786,432   packed whh bf16 MFMA B-frags (col-pair layout)
//   wih_bt  @ 19663872     786,432   [1536][256] bf16 concat(wf_ih, wb_ih)
//   wr_bt   @ 20450304     524,288   [512][512] bf16 w_rank[:, :512]
//   rank_l  @ 20974592       2,048   [512] f32 w_rank[:, 512]
//   bias2   @ 20976640       6,144   [1536] f32 b_ih + (bhh for r,z gates)
//   keys    @ 20982784   8,404,992   [8][513][512] u32 scatter-max
//   base_v  @ 29387776   8,388,608   [8][512][512] f32
//   nx      @ 37776384 134,217,728   [131072][512] bf16
//   total ≈ 172 MB

#define HH 256
#define NNODE 512
#define PLEN 64

typedef __attribute__((ext_vector_type(8))) short short8;
typedef __attribute__((ext_vector_type(4))) float f32x4;
typedef unsigned short ushort_t;
typedef __attribute__((address_space(1))) const void* gas_t;
typedef __attribute__((address_space(3))) void* las_t;

__device__ __forceinline__ f32x4 mfma16(short8 a, short8 b, f32x4 c) {
    return __builtin_amdgcn_mfma_f32_16x16x32_bf16(a, b, c, 0, 0, 0);
}
__device__ __forceinline__ ushort_t f2bf(float f) {
    unsigned u = __float_as_uint(f);
    u += 0x7fffu + ((u >> 16) & 1u);
    return (ushort_t)(u >> 16);
}
__device__ __forceinline__ float bf2f(ushort_t s) {
    return __uint_as_float(((unsigned)s) << 16);
}
__device__ __forceinline__ float sigm(float x) {
    return __builtin_amdgcn_rcpf(1.f + __expf(-x));
}
__device__ __forceinline__ float tanh_(float x) {
    return 1.f - 2.f * __builtin_amdgcn_rcpf(__expf(2.f * x) + 1.f);
}
__device__ __forceinline__ unsigned fkey(float f) {
    unsigned u = __float_as_uint(f);
    return (u & 0x80000000u) ? ~u : (u | 0x80000000u);
}
__device__ __forceinline__ float fdec(unsigned k) {
    unsigned u = (k & 0x80000000u) ? (k ^ 0x80000000u) : ~k;
    return __uint_as_float(u);
}

// xw3 remap: original col c in [0,1536) -> packed element offset within a row.
// col within dir: g*256 + w*32 + 2*lm + n  ->  w*96 + lm*6 + g*2 + n
__device__ __forceinline__ int xw3_remap(int c) {
    const int dir = c >= 768;
    const int cd = c - dir * 768;
    const int g = cd >> 8, cc = cd & 255;
    const int w2 = cc >> 5, within = cc & 31;
    return dir * 768 + w2 * 96 + (within >> 1) * 6 + g * 2 + (within & 1);
}

// ---------------- embedding token max-pool ----------------
__global__ void k_embed(const int* __restrict__ nodes, const float* __restrict__ emb,
                        float* __restrict__ x, ushort_t* __restrict__ xbf)
{
    const int bn = blockIdx.x, h = threadIdx.x;
    const int* nd = nodes + bn * 8;
    float m = -3.4e38f;
#pragma unroll
    for (int k = 0; k < 8; ++k)
        m = fmaxf(m, emb[(size_t)nd[k] * HH + h]);
    x[(size_t)bn * HH + h] = m;
    xbf[(size_t)bn * HH + h] = f2bf(m);
}

// ---------------- pack weights ----------------
__global__ void k_pack(const float* __restrict__ wf_ih, const float* __restrict__ wf_hh,
                       const float* __restrict__ bf_ih, const float* __restrict__ bf_hh,
                       const float* __restrict__ wb_ih, const float* __restrict__ wb_hh,
                       const float* __restrict__ bb_ih, const float* __restrict__ bb_hh,
                       const float* __restrict__ w_rank,
                       ushort_t* __restrict__ whhp, ushort_t* __restrict__ wih_bt,
                       ushort_t* __restrict__ wr_bt, float* __restrict__ rank_l,
                       float* __restrict__ bias2, ushort_t* __restrict__ xw3)
{
    int i = blockIdx.x * 256 + threadIdx.x;
    if (i < 393216) {
        // chunk c = ((dir*8+w)*8+kt)*6 + g*2 + n; lane l elem e:
        // whhp <- whh[g*256 + w*32 + 2*(l&15) + n][kt*32 + (l>>4)*8 + e]
        const int e = i & 7, l = (i >> 3) & 63;
        int c = i >> 9;
        const int n = c & 1; c >>= 1;
        const int g = c % 3; c /= 3;
        const int kt = c & 7; c >>= 3;
        const int w2 = c & 7;
        const int dir = c >> 3;
        const float* whh = dir ? wb_hh : wf_hh;
        whhp[i] = f2bf(whh[(g * 256 + w2 * 32 + 2 * (l & 15) + n) * 256 +
                           kt * 32 + (l >> 4) * 8 + e]);
        return;
    }
    i -= 393216;
    if (i < 393216) {   // wih_bt [1536][256]
        const int n = i >> 8, k = i & 255;
        const float* wih = (n < 768) ? wf_ih : wb_ih;
        wih_bt[i] = f2bf(wih[(n % 768) * 256 + k]);
        return;
    }
    i -= 393216;
    if (i < 262144) { wr_bt[i] = f2bf(w_rank[(i >> 9) * 513 + (i & 511)]); return; }
    i -= 262144;
    if (i < 512) { rank_l[i] = w_rank[i * 513 + 512]; return; }
    i -= 512;
    if (i < 1536) {
        const int c = i;
        const int dir = c >= 768;
        const int cd = c - dir * 768;
        const int g = cd >> 8;
        const float bi = dir ? bb_ih[cd] : bf_ih[cd];
        const float bh = (g < 2) ? (dir ? bb_hh[cd] : bf_hh[cd]) : 0.f;
        bias2[c] = bi + bh;
        xw3[(size_t)4096 * 1536 + xw3_remap(c)] = f2bf(bi + bh);  // padding row
    }
}

// ---------------- GEMM mainloop (256 thr, 128x128, BK=64; A,Bt row-major [*][K]) ----
template<int KD>
__device__ __forceinline__ void gemm_loop(const ushort_t* __restrict__ A,
                                          const ushort_t* __restrict__ Bt,
                                          ushort_t* al, ushort_t* bl,
                                          int bm, int bn, f32x4 acc[4][4])
{
    const int tid = threadIdx.x, w = tid >> 6, l = tid & 63;
    const int lm = l & 15, lh = l >> 4;
    const int wm = w >> 1, wn = w & 1;
    const int lr = l >> 3, lc = (l & 7) * 8;
    for (int k0 = 0; k0 < KD; k0 += 64) {
#pragma unroll
        for (int i = 0; i < 4; ++i) {
            const int c = w * 4 + i;
            const ushort_t* ga = A + (size_t)(bm + c * 8 + lr) * KD + k0 + lc;
            const ushort_t* gb = Bt + (size_t)(bn + c * 8 + lr) * KD + k0 + lc;
            __builtin_amdgcn_global_load_lds((gas_t)ga, (las_t)(al + c * 512), 16, 0, 0);
            __builtin_amdgcn_global_load_lds((gas_t)gb, (las_t)(bl + c * 512), 16, 0, 0);
        }
        __syncthreads();
#pragma unroll
        for (int kt = 0; kt < 2; ++kt) {
            short8 af[4], bfr[4];
            const int ko = kt * 32 + lh * 8;
#pragma unroll
            for (int m = 0; m < 4; ++m)
                af[m] = *(const short8*)(al + (wm * 64 + m * 16 + lm) * 64 + ko);
#pragma unroll
            for (int n = 0; n < 4; ++n)
                bfr[n] = *(const short8*)(bl + (wn * 64 + n * 16 + lm) * 64 + ko);
#pragma unroll
            for (int m = 0; m < 4; ++m)
#pragma unroll
                for (int n = 0; n < 4; ++n)
                    acc[m][n] = mfma16(af[m], bfr[n], acc[m][n]);
        }
        __syncthreads();
    }
}

// ---------------- xw GEMM: [4096][256] @ [256][1536] + bias2 -> packed bf16 ----------
__global__ void __launch_bounds__(256, 2)
k_gemm_xw(const ushort_t* __restrict__ xbf, const ushort_t* __restrict__ wih_bt,
          const float* __restrict__ bias2, ushort_t* __restrict__ xw3)
{
    __shared__ __align__(16) ushort_t al[128 * 64], bl[128 * 64];
    f32x4 acc[4][4] = {};
    const int bm = blockIdx.y * 128, bn = blockIdx.x * 128;
    gemm_loop<256>(xbf, wih_bt, al, bl, bm, bn, acc);
    const int tid = threadIdx.x, w = tid >> 6, l = tid & 63;
    const int lm = l & 15, lh = l >> 4, wm = w >> 1, wn = w & 1;
#pragma unroll
    for (int m = 0; m < 4; ++m)
#pragma unroll
        for (int rr = 0; rr < 4; ++rr) {
            const int row = bm + wm * 64 + m * 16 + lh * 4 + rr;
#pragma unroll
            for (int n = 0; n < 4; ++n) {
                const int col = bn + wn * 64 + n * 16 + lm;
                xw3[(size_t)row * 1536 + xw3_remap(col)] = f2bf(acc[m][n][rr] + bias2[col]);
            }
        }
}

// ---------------- GRU scan core ----------------
// 512 thr = 8 waves; wave w owns hidden cols [w*32, w*32+32) as pairs (2lm, 2lm+1)
// across all 3 gates. Bf = 48 short8 (192 regs) pinned in AGPRs; h carried in LDS.
template<bool IS_BASE>
__device__ __forceinline__ void scan_run(int dir, int sg, int tid,
    const ushort_t* __restrict__ xw3, const ushort_t* __restrict__ whhp,
    const float* __restrict__ bhh, ushort_t (*hl)[4096], const int* idr,
    ushort_t* __restrict__ nx, float* __restrict__ base_v)
{
    const int w = tid >> 6, l = tid & 63;
    const int lm = l & 15, lh = l >> 4;
    const int nsteps = IS_BASE ? NNODE : PLEN;

    short8 Bf[8][3][2];
    {
        const ushort_t* wp = whhp + (size_t)(dir * 8 + w) * 24576 + l * 8;
#pragma unroll
        for (int kt = 0; kt < 8; ++kt)
#pragma unroll
            for (int g = 0; g < 3; ++g)
#pragma unroll
                for (int n = 0; n < 2; ++n) {
                    short8 v = *(const short8*)(wp + (kt * 6 + g * 2 + n) * 512);
                    asm volatile("" : "+a"(v));   // pin into AGPR class
                    Bf[kt][g][n] = v;
                }
    }
    const float bn0 = bhh[512 + w * 32 + lm * 2];
    const float bn1 = bhh[512 + w * 32 + lm * 2 + 1];

    __syncthreads();
    for (int i = tid; i < 4096; i += 512) hl[0][i] = 0;
    __syncthreads();

    int cur = 0;
    for (int step = 0; step < nsteps; ++step) {
        const int t = dir ? (nsteps - 1 - step) : step;
        // xw gather: 12B per (lane, ri) = {r,z,n} x col-pair (hidden under MFMA)
        uint3 gv[4];
#pragma unroll
        for (int ri = 0; ri < 4; ++ri) {
            const int sq = lh * 4 + ri;
            const int row = IS_BASE ? ((sq < 8) ? ((sq << 9) + t) : 4096)
                                    : idr[(sq << 6) + t];
            gv[ri] = *(const uint3*)((const char*)xw3 +
                (size_t)row * 3072 + dir * 1536 + w * 192 + lm * 12);
        }
        // gates = h @ whh^T: M=16 seqs, own 96 gate-cols, K=256
        f32x4 acc[3][2] = {};
        const char* hb = (const char*)hl[cur];
#pragma unroll
        for (int kt = 0; kt < 8; ++kt) {
            const short8 a = *(const short8*)(hb + lm * 512 +
                ((kt * 64 + lh * 16) ^ ((lm & 7) << 4)));
#pragma unroll
            for (int g = 0; g < 3; ++g)
#pragma unroll
                for (int n = 0; n < 2; ++n)
                    acc[g][n] = mfma16(a, Bf[kt][g][n], acc[g][n]);
        }
        ushort_t* hn_ = hl[cur ^ 1];
#pragma unroll
        for (int ri = 0; ri < 4; ++ri) {
            const int sq = lh * 4 + ri;
            // h_old read back from LDS (bf16) instead of f32 register carry
            const unsigned hv = *(const unsigned*)(hb + sq * 512 +
                ((w * 64 + lm * 4) ^ ((sq & 7) << 4)));
            unsigned hpack = 0;
            float hs0 = 0.f, hs1 = 0.f;
#pragma unroll
            for (int n = 0; n < 2; ++n) {
                const float xr = bf2f((ushort_t)(n ? (gv[ri].x >> 16) : (gv[ri].x & 0xffffu)));
                const float xz = bf2f((ushort_t)(n ? (gv[ri].y >> 16) : (gv[ri].y & 0xffffu)));
                const float xn = bf2f((ushort_t)(n ? (gv[ri].z >> 16) : (gv[ri].z & 0xffffu)));
                const float hov = bf2f((ushort_t)(n ? (hv >> 16) : (hv & 0xffffu)));
                const float rr = sigm(acc[0][n][ri] + xr);
                const float zz = sigm(acc[1][n][ri] + xz);
                const float nn = tanh_(xn + rr * (acc[2][n][ri] + (n ? bn1 : bn0)));
                const float h = (1.f - zz) * nn + zz * hov;
                if (n) hs1 = h; else hs0 = h;
                hpack |= ((unsigned)f2bf(h)) << (n * 16);
            }
            *(unsigned*)((char*)hn_ + sq * 512 + ((w * 64 + lm * 4) ^ ((sq & 7) << 4))) = hpack;
            if (IS_BASE) {
                if (sq < 8)
                    *(float2*)(base_v + ((size_t)(sq * NNODE + t)) * 512 +
                               dir * 256 + w * 32 + lm * 2) = make_float2(hs0, hs1);
            } else {
                *(unsigned*)((char*)nx + (((size_t)((sg * 16 + sq) * PLEN + t)) * 512 +
                    dir * 256 + w * 32 + lm * 2) * 2) = hpack;
            }
        }
        __syncthreads();
        cur ^= 1;
    }
}

// ---------------- fused: blocks 0,1 = base GRU; 2..129 = path scan + rank GEMM ----
__global__ void __launch_bounds__(512)
__attribute__((amdgpu_waves_per_eu(2, 2)))
k_scan(const int* __restrict__ paths, const ushort_t* __restrict__ xw3,
       const ushort_t* __restrict__ whhp,
       const float* __restrict__ bf_hh, const float* __restrict__ bb_hh,
       const ushort_t* __restrict__ wr_bt, const float* __restrict__ b_rank,
       const float* __restrict__ rank_l,
       ushort_t* __restrict__ nx, float* __restrict__ base_v,
       unsigned* __restrict__ keys)
{
    __shared__ __align__(16) ushort_t hl[2][4096];
    __shared__ __align__(16) ushort_t al[8192], bl[8192];
    __shared__ int idr[1024];
    const int tid = threadIdx.x;
    const int w = tid >> 6, l = tid & 63;
    const int lm = l & 15, lh = l >> 4;

    if (blockIdx.x < 2) {
        scan_run<true>((int)blockIdx.x, 0, tid, xw3, whhp,
                       blockIdx.x ? bb_hh : bf_hh, hl, nullptr, nx, base_v);
        return;
    }
    const int sg = (int)blockIdx.x - 2;
    for (int i = tid; i < 1024; i += 512) {
        const int s = sg * 16 + (i >> 6), t = i & 63;
        const int id = paths[(s << 6) + t];
        idr[i] = (id < NNODE) ? (((s >> 8) << 9) + id) : 4096;
    }
    scan_run<false>(0, sg, tid, xw3, whhp, bf_hh, hl, idr, nx, base_v);
    scan_run<false>(1, sg, tid, xw3, whhp, bb_hh, hl, idr, nx, base_v);

    // ---- rank phase: own 1024 nx rows @ wr^T, 32 jobs of 128x128 tiles, K=512 ----
    __threadfence_block();
    __syncthreads();
    const int wm = w >> 2, wn = w & 3;   // wave tile 64x32
#pragma unroll 1
    for (int job = 0; job < 32; ++job) {
        const int mt = job >> 2, ntile = job & 3;
        const size_t ar0 = (size_t)sg * 1024 + mt * 128;
        const int n0 = ntile * 128;
        f32x4 racc[4][2] = {};
        for (int k0 = 0; k0 < 512; k0 += 64) {
#pragma unroll
            for (int i = 0; i < 2; ++i) {
                const int c = w * 128 + i * 64 + l;
                const int row = c >> 3, j = c & 7;
                const int jp = j ^ (row & 7);   // pre-swizzled source (both-sides rule)
                __builtin_amdgcn_global_load_lds(
                    (gas_t)(nx + (ar0 + row) * 512 + k0 + jp * 8),
                    (las_t)(al + c * 8), 16, 0, 0);
                __builtin_amdgcn_global_load_lds(
                    (gas_t)(wr_bt + (size_t)(n0 + row) * 512 + k0 + jp * 8),
                    (las_t)(bl + c * 8), 16, 0, 0);
            }
            __syncthreads();
#pragma unroll
            for (int kt = 0; kt < 2; ++kt) {
                short8 av[4], bv[2];
#pragma unroll
                for (int m = 0; m < 4; ++m) {
                    const int r = wm * 64 + m * 16 + lm;
                    av[m] = *(const short8*)((const char*)al + r * 128 +
                            ((kt * 64 + lh * 16) ^ ((r & 7) << 4)));
                }
#pragma unroll
                for (int n = 0; n < 2; ++n) {
                    const int r = wn * 32 + n * 16 + lm;
                    bv[n] = *(const short8*)((const char*)bl + r * 128 +
                            ((kt * 64 + lh * 16) ^ ((r & 7) << 4)));
                }
#pragma unroll
                for (int m = 0; m < 4; ++m)
#pragma unroll
                    for (int n = 0; n < 2; ++n)
                        racc[m][n] = mfma16(av[m], bv[n], racc[m][n]);
            }
            __syncthreads();
        }
#pragma unroll
        for (int m = 0; m < 4; ++m)
#pragma unroll
            for (int rr = 0; rr < 4; ++rr) {
                const size_t grow = ar0 + wm * 64 + m * 16 + lh * 4 + rr;
                const int id = paths[grow];
                const float rv = __builtin_amdgcn_rcpf((float)(((grow >> 6) & 255) + 1));
                unsigned* kp = keys + (((grow >> 14) * 513 + id) << 9);
#pragma unroll
                for (int n = 0; n < 2; ++n) {
                    const int col = n0 + wn * 32 + n * 16 + lm;
                    const float v = racc[m][n][rr] + b_rank[col] + rank_l[col] * rv;
                    if (id < NNODE) {
                        const unsigned key = fkey(v);
                        if (key > kp[col]) atomicMax(kp + col, key);
                    }
                }
            }
    }
}

// ---------------- merge: v = has ? vmax : transit(x);  all_v = base_v + v ----------------
__global__ void k_merge(const unsigned* __restrict__ keys, const float* __restrict__ base_v,
                        const float* __restrict__ x, const float* __restrict__ w_transit,
                        const float* __restrict__ b_transit, float* __restrict__ out0)
{
    const int blk = blockIdx.x;
    const int b = blk >> 9, n = blk & 511;
    const int tid = threadIdx.x;
#pragma unroll
    for (int h = 0; h < 2; ++h) {
        const int o = tid + h * 256;
        const unsigned k = keys[((size_t)(b * 513 + n)) * 512 + o];
        float v;
        if (k) {
            v = fdec(k);
        } else {
            float a = b_transit[o];
            const float* wt = w_transit + o * HH;
            const float* xr = x + ((size_t)(b * NNODE + n)) * HH;
            for (int i = 0; i < HH; ++i) a += xr[i] * wt[i];
            v = a;
        }
        const size_t oi = ((size_t)(b * NNODE + n)) * 512 + o;
        out0[oi] = base_v[oi] + v;
    }
}

// ---------------- last_state: rowmax over nodes, then @ w_h.T + b_h ----------------
__global__ void k_last(const float* __restrict__ out0, const float* __restrict__ w_h,
                       const float* __restrict__ b_h, float* __restrict__ out1)
{
    __shared__ float m[512];
    const int b = blockIdx.x, tid = threadIdx.x;
#pragma unroll
    for (int h = 0; h < 2; ++h) {
        const int o = tid + h * 256;
        float mm = -3.4e38f;
        for (int n = 0; n < NNODE; ++n)
            mm = fmaxf(mm, out0[((size_t)(b * NNODE + n)) * 512 + o]);
        m[o] = mm;
    }
    __syncthreads();
    float a = b_h[tid];
    const float* wr = w_h + tid * 512;
    for (int j = 0; j < 512; ++j) a += m[j] * wr[j];
    out1[b * HH + tid] = a;
}

extern "C" void kernel_launch(void* const* d_in, const int* in_sizes, int n_in,
                              void* d_out, int out_size, void* d_ws, size_t ws_size,
                              hipStream_t stream)
{
    (void)in_sizes; (void)n_in; (void)out_size; (void)ws_size;
    const int* nodes = (const int*)d_in[0];
    const int* paths = (const int*)d_in[1];
    const float* emb = (const float*)d_in[2];
    const float* wf_ih = (const float*)d_in[3];
    const float* wf_hh = (const float*)d_in[4];
    const float* bf_ih = (const float*)d_in[5];
    const float* bf_hh = (const float*)d_in[6];
    const float* wb_ih = (const float*)d_in[7];
    const float* wb_hh = (const float*)d_in[8];
    const float* bb_ih = (const float*)d_in[9];
    const float* bb_hh = (const float*)d_in[10];
    const float* w_transit = (const float*)d_in[11];
    const float* b_transit = (const float*)d_in[12];
    const float* w_rank = (const float*)d_in[13];
    const float* b_rank = (const float*)d_in[14];
    const float* w_h = (const float*)d_in[15];
    const float* b_h = (const float*)d_in[16];

    char* ws = (char*)d_ws;
    float* x = (float*)(ws);
    ushort_t* xbf = (ushort_t*)(ws + 4194304);
    ushort_t* xw3 = (ushort_t*)(ws + 6291456);
    ushort_t* whhp = (ushort_t*)(ws + 18877440);
    ushort_t* wih_bt = (ushort_t*)(ws + 19663872);
    ushort_t* wr_bt = (ushort_t*)(ws + 20450304);
    float* rank_l = (float*)(ws + 20974592);
    float* bias2 = (float*)(ws + 20976640);
    unsigned* keys = (unsigned*)(ws + 20982784);
    float* base_v = (float*)(ws + 29387776);
    ushort_t* nx = (ushort_t*)(ws + 37776384);

    float* out0 = (float*)d_out;
    float* out1 = out0 + 2097152;

    hipMemsetAsync(keys, 0, 8404992, stream);
    k_embed<<<4096, 256, 0, stream>>>(nodes, emb, x, xbf);
    k_pack<<<4104, 256, 0, stream>>>(wf_ih, wf_hh, bf_ih, bf_hh, wb_ih, wb_hh,
                                     bb_ih, bb_hh, w_rank,
                                     whhp, wih_bt, wr_bt, rank_l, bias2, xw3);
    k_gemm_xw<<<dim3(12, 32), 256, 0, stream>>>(xbf, wih_bt, bias2, xw3);
    k_scan<<<130, 512, 0, stream>>>(paths, xw3, whhp, bf_hh, bb_hh, wr_bt,
                                    b_rank, rank_l, nx, base_v, keys);
    k_merge<<<4096, 256, 0, stream>>>(keys, base_v, x, w_transit, b_transit, out0);
    k_last<<<8, 256, 0, stream>>>(out0, w_h, b_h, out1);
}